// Round 4
// baseline (1813.939 us; speedup 1.0000x reference)
//
#include <hip/hip_runtime.h>

// ---------------------------------------------------------------- constants
namespace {
constexpr int   B_   = 16;
constexpr int   N_   = 20000;
constexpr int   C_   = 64;
constexpr int   DIM_ = 128;
constexpr int   E_   = 640000;
constexpr int   NB_  = 3;
constexpr int   ROW_ = B_ * C_;      // 1024 elements per node row in [N,B,C]
constexpr int   NR_  = N_ * B_;      // 320000 rows of C elements

constexpr int   LDP  = 200;          // LDS row stride (shorts): 400B = 100 dwords,
                                     // 100 % 32 = 4 -> 2-way max on b128 reads (free)

// SpMM phase blocking
constexpr int   PH_   = 16;          // phases
constexpr int   PCOL_ = ROW_ / PH_;  // 64 cols (128B) per phase
constexpr int   NPB_  = 16;          // nodes per block (16 lanes each)
constexpr int   NCHK_ = N_ / NPB_;   // 1250 chunks per phase
constexpr int   NBIN_ = 1024;        // degree-sort bins
constexpr int   NXCD_ = 8;           // XCDs; blockIdx % 8 -> XCD (round-robin)
constexpr int   EP_   = E_ + 7 * N_ + 64;   // padded edge capacity (lists %8)

// bf16 weight region sizes (elements)
constexpr int   SZ1_ = 128 * 192;    // Wc^T  per block
constexpr int   SZ2_ = 128 * 128;    // w1^T  per block
constexpr int   SZ3_ = 64 * 128;     // w2^T  per block
constexpr int   SZB_ = SZ1_ + SZ2_ + SZ3_;
constexpr int   WTOT_ = NB_ * SZB_;

// workspace layout (bytes)
constexpr size_t SZH_  = (size_t)N_ * ROW_ * sizeof(float);   // fp32 h
constexpr size_t SZHB_ = (size_t)N_ * ROW_ * 2;               // bf16 row image
constexpr size_t OFF_H    = 0;
constexpr size_t OFF_HB   = SZH_;
constexpr size_t OFF_T1B  = OFF_HB  + SZHB_;
constexpr size_t OFF_SB   = OFF_T1B + SZHB_;
constexpr size_t OFF_DEG  = OFF_SB  + SZHB_;
constexpr size_t OFF_CNT  = OFF_DEG + (size_t)N_ * 4;
constexpr size_t OFF_OFFS = OFF_CNT + (size_t)N_ * 4;
constexpr size_t OFF_CV   = ((OFF_OFFS + (size_t)(N_ + 1) * 4 + 255) / 256) * 256;
// esrc (u16[EP_]) + eww (f32[EP_]) live inside the old 8B-cv footprint
constexpr size_t OFF_ESRC = OFF_CV;
constexpr size_t OFF_EW   = ((OFF_ESRC + (size_t)EP_ * 2 + 255) / 256) * 256;
static_assert(OFF_EW + (size_t)EP_ * 4 <= OFF_CV + (size_t)E_ * 8, "cv region overflow");
constexpr size_t OFF_PERM = OFF_CV   + (size_t)E_ * 8;
constexpr size_t OFF_HIST = OFF_PERM + (size_t)N_ * 4;
constexpr size_t OFF_HOFF = OFF_HIST + (size_t)NBIN_ * 4;
constexpr size_t OFF_HFIL = OFF_HOFF + (size_t)NBIN_ * 4;
constexpr size_t OFF_WTC  = OFF_HFIL + (size_t)NBIN_ * 4;
constexpr size_t OFF_WT1  = OFF_WTC + (size_t)NB_ * SZ1_ * 2;
constexpr size_t OFF_WT2  = OFF_WT1 + (size_t)NB_ * SZ2_ * 2;
// total ~210 MB
} // namespace

typedef short s16x8 __attribute__((ext_vector_type(8)));
typedef float f32x4 __attribute__((ext_vector_type(4)));
typedef float f32x2 __attribute__((ext_vector_type(2)));
typedef unsigned int u32;
typedef u32   u32x4 __attribute__((ext_vector_type(4)));
typedef u32   u32x2 __attribute__((ext_vector_type(2)));

__device__ __forceinline__ u32 bfr(float x) {
    u32 u = __float_as_uint(x);
    return (u + 0x7FFFu + ((u >> 16) & 1u)) >> 16;
}
__device__ __forceinline__ u32 pack_bf2(float x, float y) {
    return bfr(x) | (bfr(y) << 16);
}
__device__ __forceinline__ float bflo(u32 u) { return __uint_as_float(u << 16); }
__device__ __forceinline__ float bfhi(u32 u) { return __uint_as_float(u & 0xFFFF0000u); }
// {lo,hi} bf16 pair -> f32x2 (feeds v_pk_fma_f32)
__device__ __forceinline__ f32x2 bfpair(u32 u) {
    u32x2 r;
    r.x = u << 16;
    r.y = u & 0xFFFF0000u;
    return __builtin_bit_cast(f32x2, r);
}

// ---------------------------------------------------------------- graph prep
__global__ void deg_cnt_k(const int* __restrict__ src, const int* __restrict__ dst,
                          const float* __restrict__ ew,
                          float* __restrict__ deg, int* __restrict__ cnt) {
    int e = blockIdx.x * 256 + threadIdx.x;
    if (e < E_) {
        atomicAdd(deg + src[e], ew[e]);
        atomicAdd(cnt + dst[e], 1);
    }
}

__global__ void dinv_k(float* __restrict__ deg) {
    int i = blockIdx.x * 256 + threadIdx.x;
    if (i < N_) {
        float d = deg[i];
        deg[i] = (d > 0.f) ? rsqrtf(fmaxf(d, 1e-12f)) : 0.f;
    }
}

// exclusive scan of per-node counts PADDED to multiples of 8 (branch-free spmm)
__global__ __launch_bounds__(1024) void scan_k(const int* __restrict__ cnt,
                                               int* __restrict__ offs) {
    __shared__ int sums[1024];
    const int tid = threadIdx.x;
    constexpr int CH = (N_ + 1023) / 1024;   // 20
    const int base = tid * CH;
    int local = 0;
    for (int j = 0; j < CH; ++j) {
        int i = base + j;
        if (i < N_) local += (cnt[i] + 7) & ~7;
    }
    sums[tid] = local;
    __syncthreads();
    for (int off = 1; off < 1024; off <<= 1) {
        int v = sums[tid];
        int u = (tid >= off) ? sums[tid - off] : 0;
        __syncthreads();
        sums[tid] = v + u;
        __syncthreads();
    }
    int run = (tid > 0) ? sums[tid - 1] : 0;
    for (int j = 0; j < CH; ++j) {
        int i = base + j;
        if (i < N_) { offs[i] = run; run += (cnt[i] + 7) & ~7; }
    }
    if (tid == 1023) offs[N_] = sums[1023];
}

// degree histogram / scan / perm-scatter (degree-sorted node order)
__global__ void hist_k(const int* __restrict__ cnt, int* __restrict__ hist) {
    int i = blockIdx.x * 256 + threadIdx.x;
    if (i < N_) atomicAdd(hist + min(cnt[i], NBIN_ - 1), 1);
}

__global__ __launch_bounds__(1024) void hscan_k(const int* __restrict__ hist,
                                                int* __restrict__ hoffs) {
    __shared__ int s[NBIN_];
    int t = threadIdx.x;
    s[t] = hist[t];
    __syncthreads();
    for (int off = 1; off < NBIN_; off <<= 1) {
        int v = s[t];
        int u = (t >= off) ? s[t - off] : 0;
        __syncthreads();
        s[t] = v + u;
        __syncthreads();
    }
    hoffs[t] = (t > 0) ? s[t - 1] : 0;
}

__global__ void permscatter_k(const int* __restrict__ cnt, const int* __restrict__ hoffs,
                              int* __restrict__ hfill, int* __restrict__ perm) {
    int i = blockIdx.x * 256 + threadIdx.x;
    if (i < N_) {
        int b = min(cnt[i], NBIN_ - 1);
        int pos = hoffs[b] + atomicAdd(hfill + b, 1);
        perm[pos] = i;
    }
}

// split edge store: u16 src + f32 weight (6B/edge, was 8B). pads stay 0 (memset).
__global__ void scatter_k(const int* __restrict__ src, const int* __restrict__ dst,
                          const float* __restrict__ ew, const float* __restrict__ dinv,
                          const int* __restrict__ offs, int* __restrict__ fill,
                          ushort* __restrict__ esrc, float* __restrict__ eww) {
    int e = blockIdx.x * 256 + threadIdx.x;
    if (e < E_) {
        int s = src[e], d = dst[e];
        int pos = offs[d] + atomicAdd(fill + d, 1);
        float w = -dinv[s] * ew[e] * dinv[d];
        esrc[pos] = (ushort)s;
        eww[pos]  = w;
    }
}

// ---------------------------------------------------------------- bf16 weight prep
__global__ void wprep_k(const float* __restrict__ cw, const float* __restrict__ w1,
                        const float* __restrict__ w2,
                        short* __restrict__ wtc, short* __restrict__ wt1,
                        short* __restrict__ wt2) {
    int idx = blockIdx.x * 256 + threadIdx.x;
    if (idx >= WTOT_) return;
    int b = idx / SZB_;
    int rem = idx - b * SZB_;
    if (rem < SZ1_) {
        int n = rem / 192, k = rem - n * 192;
        int part = k >> 6, c = k & 63;
        const float* base = cw + (size_t)b * 3 * 64 * 128;
        float v;
        if (part == 0)      v = base[c * 128 + n] - base[16384 + c * 128 + n];
        else if (part == 1) v = base[8192 + c * 128 + n];
        else                v = 2.f * base[16384 + c * 128 + n];
        wtc[(size_t)b * SZ1_ + n * 192 + k] = (short)bfr(v);
    } else if (rem < SZ1_ + SZ2_) {
        int r2 = rem - SZ1_;
        int n = r2 >> 7, k = r2 & 127;
        float v = w1[(size_t)b * 16384 + k * 128 + n];
        wt1[(size_t)b * SZ2_ + n * 128 + k] = (short)bfr(v);
    } else {
        int r3 = rem - SZ1_ - SZ2_;
        int n = r3 >> 7, k = r3 & 127;
        float v = w2[(size_t)b * 8192 + k * 64 + n];
        wt2[(size_t)b * SZ3_ + n * 128 + k] = (short)bfr(v);
    }
}

// ---------------------------------------------------------------- transposes
__global__ void transpose_in_k(const float* __restrict__ x, float* __restrict__ h,
                               ushort* __restrict__ hb) {
    int idx = blockIdx.x * 256 + threadIdx.x;
    int c4 = idx & 15;
    int nb = idx >> 4;        // n*B + b
    int b  = nb & (B_ - 1);
    int n  = nb >> 4;
    const float4 v = *(const float4*)(x + ((size_t)b * N_ + n) * C_ + (c4 << 2));
    *(float4*)(h + (size_t)nb * C_ + (c4 << 2)) = v;
    uint2 p;
    p.x = pack_bf2(v.x, v.y);
    p.y = pack_bf2(v.z, v.w);
    *(uint2*)(hb + (size_t)nb * C_ + (c4 << 2)) = p;
}

__global__ void transpose_out_k(const float* __restrict__ h, float* __restrict__ out) {
    int idx = blockIdx.x * 256 + threadIdx.x;
    int c4 = idx & 15;
    int nb = idx >> 4;
    int b  = nb & (B_ - 1);
    int n  = nb >> 4;
    const float4 v = *(const float4*)(h + (size_t)nb * C_ + (c4 << 2));
    *(float4*)(out + ((size_t)b * N_ + n) * C_ + (c4 << 2)) = v;
}

// ---------------------------------------------------------------- SpMM, phase-blocked
// XCD-pinned phases (r7) + pipelined 8-edge loop (r8) + L2-protection (r9).
// r8 post-mortem: dur pinned at ~134us = 1.31 GB gather / ~10 TB/s => gathers
// were served by L3, not L2 -- the 4.2 MB/phase metadata stream + 2.56 MB
// write-allocate thrashed the 2.56 MB hot slice out of the 4 MB XCD L2.
// r9: metadata loads and output stores are NONTEMPORAL (no L2 pollution), so
// L2 holds only the gather slice. FMA accumulation packed f32x2 (v_pk_fma_f32).
__global__ __launch_bounds__(256) void spmm_ph_k(const ushort* __restrict__ in,
                                                 ushort* __restrict__ out,
                                                 const int* __restrict__ offs,
                                                 const ushort* __restrict__ esrc,
                                                 const float* __restrict__ eww,
                                                 const int* __restrict__ perm) {
    const int b    = blockIdx.x;
    const int xcd  = b & (NXCD_ - 1);
    const int slot = b >> 3;                    // 0..2499
    const int half = (slot >= NCHK_) ? 1 : 0;
    const int ph   = (xcd << 1) | half;
    const int chunk = slot - (half ? NCHK_ : 0);
    const int g      = threadIdx.x >> 4;
    const int lane16 = threadIdx.x & 15;
    const int n = perm[chunk * NPB_ + g];
    const int s0 = offs[n], s1 = offs[n + 1];
    const ushort* inp = in + (size_t)ph * PCOL_ + (lane16 << 2);

    f32x2 a01 = {0.f, 0.f}, a23 = {0.f, 0.f};
    if (s0 < s1) {
        u32x4 sp = __builtin_nontemporal_load((const u32x4*)(esrc + s0));
        f32x4 w0 = __builtin_nontemporal_load((const f32x4*)(eww + s0));
        f32x4 w1 = __builtin_nontemporal_load((const f32x4*)(eww + s0 + 4));
        for (int i = s0; i < s1; ) {
            const int inext = i + 8;
            uint2 v0 = *(const uint2*)(inp + ((sp.x & 0xFFFFu) << 10));
            uint2 v1 = *(const uint2*)(inp + ((sp.x >> 16)     << 10));
            uint2 v2 = *(const uint2*)(inp + ((sp.y & 0xFFFFu) << 10));
            uint2 v3 = *(const uint2*)(inp + ((sp.y >> 16)     << 10));
            uint2 v4 = *(const uint2*)(inp + ((sp.z & 0xFFFFu) << 10));
            uint2 v5 = *(const uint2*)(inp + ((sp.z >> 16)     << 10));
            uint2 v6 = *(const uint2*)(inp + ((sp.w & 0xFFFFu) << 10));
            uint2 v7 = *(const uint2*)(inp + ((sp.w >> 16)     << 10));
            // prefetch next metadata (nontemporal; stays inside padded EP_)
            u32x4 sp_n = __builtin_nontemporal_load((const u32x4*)(esrc + inext));
            f32x4 w0_n = __builtin_nontemporal_load((const f32x4*)(eww + inext));
            f32x4 w1_n = __builtin_nontemporal_load((const f32x4*)(eww + inext + 4));
            a01 += (f32x2){w0.x, w0.x} * bfpair(v0.x);
            a23 += (f32x2){w0.x, w0.x} * bfpair(v0.y);
            a01 += (f32x2){w0.y, w0.y} * bfpair(v1.x);
            a23 += (f32x2){w0.y, w0.y} * bfpair(v1.y);
            a01 += (f32x2){w0.z, w0.z} * bfpair(v2.x);
            a23 += (f32x2){w0.z, w0.z} * bfpair(v2.y);
            a01 += (f32x2){w0.w, w0.w} * bfpair(v3.x);
            a23 += (f32x2){w0.w, w0.w} * bfpair(v3.y);
            a01 += (f32x2){w1.x, w1.x} * bfpair(v4.x);
            a23 += (f32x2){w1.x, w1.x} * bfpair(v4.y);
            a01 += (f32x2){w1.y, w1.y} * bfpair(v5.x);
            a23 += (f32x2){w1.y, w1.y} * bfpair(v5.y);
            a01 += (f32x2){w1.z, w1.z} * bfpair(v6.x);
            a23 += (f32x2){w1.z, w1.z} * bfpair(v6.y);
            a01 += (f32x2){w1.w, w1.w} * bfpair(v7.x);
            a23 += (f32x2){w1.w, w1.w} * bfpair(v7.y);
            sp = sp_n; w0 = w0_n; w1 = w1_n;
            i = inext;
        }
    }
    u32x2 p;
    p.x = pack_bf2(a01.x, a01.y);
    p.y = pack_bf2(a23.x, a23.y);
    __builtin_nontemporal_store(p,
        (u32x2*)(out + (size_t)n * ROW_ + (size_t)ph * PCOL_ + (lane16 << 2)));
}

// ---------------------------------------------------------------- MFMA MLP block
// Column-sliced wave partition (r6): each of the 4 waves owns 32/128 cols
// (16/64 for stage 3) across ALL 64 rows; weight fragments live in register
// arrays (batched loads). A-tile [64x192]=[hb|t1b|sb] reg-staged into LDS once;
// g1/g2 alias the same buffer between barriers. LDS 25600B, stride 200 shorts.
__global__ __launch_bounds__(256, 4) void mlp_mfma_k(
        float* __restrict__ h, ushort* __restrict__ hb,
        const ushort* __restrict__ t1b, const ushort* __restrict__ sb,
        const short* __restrict__ wtc, const short* __restrict__ wt1,
        const short* __restrict__ wt2,
        const float* __restrict__ cbias, const float* __restrict__ b1,
        const float* __restrict__ b2, const float* __restrict__ betap) {
    __shared__ __align__(16) short u[64 * LDP];

    const int tid  = threadIdx.x;
    const int wv   = tid >> 6;
    const int lane = tid & 63;
    const int m    = lane & 15;
    const int q    = lane >> 4;
    const int row0 = blockIdx.x * 64;
    const float sp    = __logf(1.f + __expf(betap[0]));
    const float inv11 = 1.0f / 1.1f;

    // ---- stage-1 weight fragments (12): cols n = wv*32 + t*16 + m, k = kb*32+q*8
    s16x8 wA[6][2];
#pragma unroll
    for (int kb = 0; kb < 6; ++kb)
#pragma unroll
        for (int t = 0; t < 2; ++t)
            wA[kb][t] = *(const s16x8*)(wtc + ((wv << 5) + (t << 4) + m) * 192
                                            + (kb << 5) + (q << 3));

    // ---- cooperative A-tile fill: [64 rows][192 cols] = [hb|t1b|sb], batched
    {
        const ushort* srcs[3] = { hb, t1b, sb };
        s16x8 tv[3][2];
#pragma unroll
        for (int s = 0; s < 3; ++s)
#pragma unroll
            for (int i = 0; i < 2; ++i) {
                int ck = tid + (i << 8);            // 0..511
                int r = ck >> 3, c8 = ck & 7;
                tv[s][i] = *(const s16x8*)(srcs[s] + (size_t)(row0 + r) * C_ + (c8 << 3));
            }
#pragma unroll
        for (int s = 0; s < 3; ++s)
#pragma unroll
            for (int i = 0; i < 2; ++i) {
                int ck = tid + (i << 8);
                int r = ck >> 3, c8 = ck & 7;
                *(s16x8*)(u + r * LDP + (s << 6) + (c8 << 3)) = tv[s][i];
            }
    }
    __syncthreads();

    // ---- stage 1: A(64x192) @ Wc^T-slice -> acc[rg][t] (64 rows x 32 cols/wave)
    f32x4 acc[4][2];
#pragma unroll
    for (int rg = 0; rg < 4; ++rg)
#pragma unroll
        for (int t = 0; t < 2; ++t) acc[rg][t] = (f32x4){0.f, 0.f, 0.f, 0.f};
#pragma unroll
    for (int kb = 0; kb < 6; ++kb)
#pragma unroll
        for (int rg = 0; rg < 4; ++rg) {
            s16x8 af = *(const s16x8*)(u + ((rg << 4) + m) * LDP + (kb << 5) + (q << 3));
            acc[rg][0] = __builtin_amdgcn_mfma_f32_16x16x32_bf16(af, wA[kb][0], acc[rg][0], 0, 0, 0);
            acc[rg][1] = __builtin_amdgcn_mfma_f32_16x16x32_bf16(af, wA[kb][1], acc[rg][1], 0, 0, 0);
        }
    __syncthreads();   // all waves done reading A-tile; u now becomes g1

    // stage-2 weight prefetch (overlaps epilogue-1 VALU; wA is dead now)
    s16x8 wB[4][2];
#pragma unroll
    for (int k4 = 0; k4 < 4; ++k4)
#pragma unroll
        for (int t = 0; t < 2; ++t)
            wB[k4][t] = *(const s16x8*)(wt1 + (((wv << 5) + (t << 4) + m) << 7)
                                            + (k4 << 5) + (q << 3));

    // ---- epilogue 1: bias + swish -> g1 (cols wv*32..wv*32+31, all 64 rows)
    {
        float cb0 = cbias[(wv << 5) + m];
        float cb1 = cbias[(wv << 5) + 16 + m];
#pragma unroll
        for (int rg = 0; rg < 4; ++rg)
#pragma unroll
            for (int t = 0; t < 2; ++t) {
                float bv = t ? cb1 : cb0;
#pragma unroll
                for (int r = 0; r < 4; ++r) {
                    float o = acc[rg][t][r] + bv;
                    float g = o * (1.f / (1.f + __expf(-o * sp))) * inv11;
                    u[((rg << 4) + (q << 2) + r) * LDP + (wv << 5) + (t << 4) + m] =
                        (short)bfr(g);
                }
            }
    }
    __syncthreads();

    // ---- stage 2: g1(64x128) @ w1^T-slice
    f32x4 acc2[4][2];
#pragma unroll
    for (int rg = 0; rg < 4; ++rg)
#pragma unroll
        for (int t = 0; t < 2; ++t) acc2[rg][t] = (f32x4){0.f, 0.f, 0.f, 0.f};
#pragma unroll
    for (int k4 = 0; k4 < 4; ++k4)
#pragma unroll
        for (int rg = 0; rg < 4; ++rg) {
            s16x8 af = *(const s16x8*)(u + ((rg << 4) + m) * LDP + (k4 << 5) + (q << 3));
            acc2[rg][0] = __builtin_amdgcn_mfma_f32_16x16x32_bf16(af, wB[k4][0], acc2[rg][0], 0, 0, 0);
            acc2[rg][1] = __builtin_amdgcn_mfma_f32_16x16x32_bf16(af, wB[k4][1], acc2[rg][1], 0, 0, 0);
        }
    __syncthreads();   // all waves done reading g1; u now becomes g2

    // stage-3 weight prefetch (overlaps epilogue-2 VALU)
    s16x8 wC[4];
#pragma unroll
    for (int k4 = 0; k4 < 4; ++k4)
        wC[k4] = *(const s16x8*)(wt2 + (((wv << 4) + m) << 7) + (k4 << 5) + (q << 3));

    // ---- epilogue 2: bias + swish -> g2
    {
        float b10 = b1[(wv << 5) + m];
        float b11 = b1[(wv << 5) + 16 + m];
#pragma unroll
        for (int rg = 0; rg < 4; ++rg)
#pragma unroll
            for (int t = 0; t < 2; ++t) {
                float bv = t ? b11 : b10;
#pragma unroll
                for (int r = 0; r < 4; ++r) {
                    float o = acc2[rg][t][r] + bv;
                    float g = o * (1.f / (1.f + __expf(-o * sp))) * inv11;
                    u[((rg << 4) + (q << 2) + r) * LDP + (wv << 5) + (t << 4) + m] =
                        (short)bfr(g);
                }
            }
    }
    __syncthreads();

    // ---- stage 3: g2(64x128) @ w2^T-slice -> 16 cols/wave
    f32x4 acc3[4];
#pragma unroll
    for (int rg = 0; rg < 4; ++rg) acc3[rg] = (f32x4){0.f, 0.f, 0.f, 0.f};
#pragma unroll
    for (int k4 = 0; k4 < 4; ++k4)
#pragma unroll
        for (int rg = 0; rg < 4; ++rg) {
            s16x8 af = *(const s16x8*)(u + ((rg << 4) + m) * LDP + (k4 << 5) + (q << 3));
            acc3[rg] = __builtin_amdgcn_mfma_f32_16x16x32_bf16(af, wC[k4], acc3[rg], 0, 0, 0);
        }

    // ---- epilogue 3: residual h += f (batched h loads), refresh hb
    {
        float b2v = b2[(wv << 4) + m];
        float hv[4][4];
#pragma unroll
        for (int rg = 0; rg < 4; ++rg)
#pragma unroll
            for (int r = 0; r < 4; ++r)
                hv[rg][r] = h[(size_t)(row0 + (rg << 4) + (q << 2) + r) * C_
                              + (wv << 4) + m];
#pragma unroll
        for (int rg = 0; rg < 4; ++rg)
#pragma unroll
            for (int r = 0; r < 4; ++r) {
                size_t eidx = (size_t)(row0 + (rg << 4) + (q << 2) + r) * C_
                              + (wv << 4) + m;
                float nv = hv[rg][r] + acc3[rg][r] + b2v;
                h[eidx]  = nv;
                hb[eidx] = (ushort)bfr(nv);
            }
    }
}

// ---------------------------------------------------------------- launch
extern "C" void kernel_launch(void* const* d_in, const int* in_sizes, int n_in,
                              void* d_out, int out_size, void* d_ws, size_t ws_size,
                              hipStream_t stream) {
    const float* x    = (const float*)d_in[0];
    const int*   ei   = (const int*)d_in[1];
    const float* ew   = (const float*)d_in[2];
    const float* cw   = (const float*)d_in[3];
    const float* cb   = (const float*)d_in[4];
    const float* beta = (const float*)d_in[5];
    const float* w1   = (const float*)d_in[6];
    const float* b1   = (const float*)d_in[7];
    const float* w2   = (const float*)d_in[8];
    const float* b2   = (const float*)d_in[9];
    float* out = (float*)d_out;

    char* ws = (char*)d_ws;
    float*  h_t  = (float*) (ws + OFF_H);
    ushort* hb   = (ushort*)(ws + OFF_HB);
    ushort* t1b  = (ushort*)(ws + OFF_T1B);
    ushort* sb   = (ushort*)(ws + OFF_SB);
    float*  deg  = (float*) (ws + OFF_DEG);
    int*    cnt  = (int*)   (ws + OFF_CNT);
    int*    offs = (int*)   (ws + OFF_OFFS);
    ushort* esrc = (ushort*)(ws + OFF_ESRC);
    float*  eww  = (float*) (ws + OFF_EW);
    int*    perm = (int*)   (ws + OFF_PERM);
    int*    hist = (int*)   (ws + OFF_HIST);
    int*    hoff = (int*)   (ws + OFF_HOFF);
    int*    hfil = (int*)   (ws + OFF_HFIL);
    short*  wtc  = (short*) (ws + OFF_WTC);
    short*  wt1  = (short*) (ws + OFF_WT1);
    short*  wt2  = (short*) (ws + OFF_WT2);

    const int* srcI = ei;
    const int* dstI = ei + E_;

    // graph prep
    hipMemsetAsync(deg, 0, (size_t)N_ * 4, stream);
    hipMemsetAsync(cnt, 0, (size_t)N_ * 4, stream);
    hipMemsetAsync(hist, 0, (size_t)NBIN_ * 4, stream);
    hipMemsetAsync(hfil, 0, (size_t)NBIN_ * 4, stream);
    hipMemsetAsync(esrc, 0, (size_t)EP_ * 2, stream);   // pad entries: src=0
    hipMemsetAsync(eww,  0, (size_t)EP_ * 4, stream);   // pad entries: w=0
    deg_cnt_k<<<(E_ + 255) / 256, 256, 0, stream>>>(srcI, dstI, ew, deg, cnt);
    dinv_k<<<(N_ + 255) / 256, 256, 0, stream>>>(deg);
    scan_k<<<1, 1024, 0, stream>>>(cnt, offs);
    hist_k<<<(N_ + 255) / 256, 256, 0, stream>>>(cnt, hist);
    hscan_k<<<1, NBIN_, 0, stream>>>(hist, hoff);
    permscatter_k<<<(N_ + 255) / 256, 256, 0, stream>>>(cnt, hoff, hfil, perm);
    hipMemsetAsync(cnt, 0, (size_t)N_ * 4, stream);
    scatter_k<<<(E_ + 255) / 256, 256, 0, stream>>>(srcI, dstI, ew, deg, offs, cnt,
                                                    esrc, eww);

    // bf16 weights
    wprep_k<<<(WTOT_ + 255) / 256, 256, 0, stream>>>(cw, w1, w2, wtc, wt1, wt2);

    // x -> [N,B,C] (fp32 + bf16 image)
    transpose_in_k<<<(N_ * B_ * 16) / 256, 256, 0, stream>>>(x, h_t, hb);

    for (int b = 0; b < NB_; ++b) {
        spmm_ph_k<<<PH_ * NCHK_, 256, 0, stream>>>(hb, t1b, offs, esrc, eww, perm);
        spmm_ph_k<<<PH_ * NCHK_, 256, 0, stream>>>(t1b, sb, offs, esrc, eww, perm);
        mlp_mfma_k<<<NR_ / 64, 256, 0, stream>>>(h_t, hb, t1b, sb,
                                                 wtc + (size_t)b * SZ1_,
                                                 wt1 + (size_t)b * SZ2_,
                                                 wt2 + (size_t)b * SZ3_,
                                                 cb + (size_t)b * DIM_,
                                                 b1 + (size_t)b * DIM_,
                                                 b2 + (size_t)b * C_,
                                                 beta + b);
    }

    // [N,B,C] -> out
    transpose_out_k<<<(N_ * B_ * 16) / 256, 256, 0, stream>>>(h_t, out);
}

// Round 5
// 1276.228 us; speedup vs baseline: 1.4213x; 1.4213x over previous
//
#include <hip/hip_runtime.h>

// ---------------------------------------------------------------- constants
namespace {
constexpr int   B_   = 16;
constexpr int   N_   = 20000;
constexpr int   C_   = 64;
constexpr int   DIM_ = 128;
constexpr int   E_   = 640000;
constexpr int   NB_  = 3;
constexpr int   ROW_ = B_ * C_;      // 1024 elements per node row in [N,B,C]
constexpr int   NR_  = N_ * B_;      // 320000 rows of C elements

constexpr int   LDP  = 200;          // LDS row stride (shorts) for MLP kernel

// SpMM superphase blocking (r10): 8 superphases x 128 cols (256B), lane16
// owns 8 cols (16B uint4 gathers)
constexpr int   SPH_  = 8;           // superphases == XCD count
constexpr int   PC2_  = ROW_ / SPH_; // 128 cols per superphase
constexpr int   NPB_  = 16;          // nodes per block (16 lanes each)
constexpr int   NCHK_ = N_ / NPB_;   // 1250 chunks per superphase
constexpr int   NBIN_ = 1024;        // degree-sort bins
constexpr int   EP_   = E_ + 3 * N_ + 64;   // padded edge capacity (lists %4)

// bf16 weight region sizes (elements)
constexpr int   SZ1_ = 128 * 192;    // Wc^T  per block
constexpr int   SZ2_ = 128 * 128;    // w1^T  per block
constexpr int   SZ3_ = 64 * 128;     // w2^T  per block
constexpr int   SZB_ = SZ1_ + SZ2_ + SZ3_;
constexpr int   WTOT_ = NB_ * SZB_;

// workspace layout (bytes)
constexpr size_t SZH_  = (size_t)N_ * ROW_ * sizeof(float);   // fp32 h
constexpr size_t SZHB_ = (size_t)N_ * ROW_ * 2;               // bf16 row image
constexpr size_t OFF_H    = 0;
constexpr size_t OFF_HB   = SZH_;
constexpr size_t OFF_T1B  = OFF_HB  + SZHB_;
constexpr size_t OFF_SB   = OFF_T1B + SZHB_;
constexpr size_t OFF_DEG  = OFF_SB  + SZHB_;
constexpr size_t OFF_CNT  = OFF_DEG + (size_t)N_ * 4;
constexpr size_t OFF_OFFS = OFF_CNT + (size_t)N_ * 4;
constexpr size_t OFF_CV   = ((OFF_OFFS + (size_t)(N_ + 1) * 4 + 255) / 256) * 256;
// esrc (u16[EP_]) + eww (f32[EP_]) live inside the old 8B-cv footprint
constexpr size_t OFF_ESRC = OFF_CV;
constexpr size_t OFF_EW   = ((OFF_ESRC + (size_t)EP_ * 2 + 255) / 256) * 256;
static_assert(OFF_EW + (size_t)EP_ * 4 <= OFF_CV + (size_t)E_ * 8, "cv region overflow");
constexpr size_t OFF_PERM = OFF_CV   + (size_t)E_ * 8;
constexpr size_t OFF_HIST = OFF_PERM + (size_t)N_ * 4;
constexpr size_t OFF_HOFF = OFF_HIST + (size_t)NBIN_ * 4;
constexpr size_t OFF_HFIL = OFF_HOFF + (size_t)NBIN_ * 4;
constexpr size_t OFF_WTC  = OFF_HFIL + (size_t)NBIN_ * 4;
constexpr size_t OFF_WT1  = OFF_WTC + (size_t)NB_ * SZ1_ * 2;
constexpr size_t OFF_WT2  = OFF_WT1 + (size_t)NB_ * SZ2_ * 2;
// total ~210 MB
} // namespace

typedef short s16x8 __attribute__((ext_vector_type(8)));
typedef float f32x4 __attribute__((ext_vector_type(4)));
typedef float f32x2 __attribute__((ext_vector_type(2)));
typedef unsigned int u32;
typedef u32   u32x4 __attribute__((ext_vector_type(4)));
typedef u32   u32x2 __attribute__((ext_vector_type(2)));
typedef unsigned short u16;
typedef u16   u16x4 __attribute__((ext_vector_type(4)));

__device__ __forceinline__ u32 bfr(float x) {
    u32 u = __float_as_uint(x);
    return (u + 0x7FFFu + ((u >> 16) & 1u)) >> 16;
}
__device__ __forceinline__ u32 pack_bf2(float x, float y) {
    return bfr(x) | (bfr(y) << 16);
}
// {lo,hi} bf16 pair -> f32x2 (feeds v_pk_fma_f32)
__device__ __forceinline__ f32x2 bfpair(u32 u) {
    u32x2 r;
    r.x = u << 16;
    r.y = u & 0xFFFF0000u;
    return __builtin_bit_cast(f32x2, r);
}

// ---------------------------------------------------------------- graph prep
__global__ void deg_cnt_k(const int* __restrict__ src, const int* __restrict__ dst,
                          const float* __restrict__ ew,
                          float* __restrict__ deg, int* __restrict__ cnt) {
    int e = blockIdx.x * 256 + threadIdx.x;
    if (e < E_) {
        atomicAdd(deg + src[e], ew[e]);
        atomicAdd(cnt + dst[e], 1);
    }
}

__global__ void dinv_k(float* __restrict__ deg) {
    int i = blockIdx.x * 256 + threadIdx.x;
    if (i < N_) {
        float d = deg[i];
        deg[i] = (d > 0.f) ? rsqrtf(fmaxf(d, 1e-12f)) : 0.f;
    }
}

// exclusive scan of per-node counts PADDED to multiples of 4 (branch-free spmm)
__global__ __launch_bounds__(1024) void scan_k(const int* __restrict__ cnt,
                                               int* __restrict__ offs) {
    __shared__ int sums[1024];
    const int tid = threadIdx.x;
    constexpr int CH = (N_ + 1023) / 1024;   // 20
    const int base = tid * CH;
    int local = 0;
    for (int j = 0; j < CH; ++j) {
        int i = base + j;
        if (i < N_) local += (cnt[i] + 3) & ~3;
    }
    sums[tid] = local;
    __syncthreads();
    for (int off = 1; off < 1024; off <<= 1) {
        int v = sums[tid];
        int u = (tid >= off) ? sums[tid - off] : 0;
        __syncthreads();
        sums[tid] = v + u;
        __syncthreads();
    }
    int run = (tid > 0) ? sums[tid - 1] : 0;
    for (int j = 0; j < CH; ++j) {
        int i = base + j;
        if (i < N_) { offs[i] = run; run += (cnt[i] + 3) & ~3; }
    }
    if (tid == 1023) offs[N_] = sums[1023];
}

// degree histogram / scan / perm-scatter (degree-sorted node order)
__global__ void hist_k(const int* __restrict__ cnt, int* __restrict__ hist) {
    int i = blockIdx.x * 256 + threadIdx.x;
    if (i < N_) atomicAdd(hist + min(cnt[i], NBIN_ - 1), 1);
}

__global__ __launch_bounds__(1024) void hscan_k(const int* __restrict__ hist,
                                                int* __restrict__ hoffs) {
    __shared__ int s[NBIN_];
    int t = threadIdx.x;
    s[t] = hist[t];
    __syncthreads();
    for (int off = 1; off < NBIN_; off <<= 1) {
        int v = s[t];
        int u = (t >= off) ? s[t - off] : 0;
        __syncthreads();
        s[t] = v + u;
        __syncthreads();
    }
    hoffs[t] = (t > 0) ? s[t - 1] : 0;
}

__global__ void permscatter_k(const int* __restrict__ cnt, const int* __restrict__ hoffs,
                              int* __restrict__ hfill, int* __restrict__ perm) {
    int i = blockIdx.x * 256 + threadIdx.x;
    if (i < N_) {
        int b = min(cnt[i], NBIN_ - 1);
        int pos = hoffs[b] + atomicAdd(hfill + b, 1);
        perm[pos] = i;
    }
}

// split edge store: u16 src + f32 weight (6B/edge). pads stay 0 (memset).
__global__ void scatter_k(const int* __restrict__ src, const int* __restrict__ dst,
                          const float* __restrict__ ew, const float* __restrict__ dinv,
                          const int* __restrict__ offs, int* __restrict__ fill,
                          ushort* __restrict__ esrc, float* __restrict__ eww) {
    int e = blockIdx.x * 256 + threadIdx.x;
    if (e < E_) {
        int s = src[e], d = dst[e];
        int pos = offs[d] + atomicAdd(fill + d, 1);
        float w = -dinv[s] * ew[e] * dinv[d];
        esrc[pos] = (ushort)s;
        eww[pos]  = w;
    }
}

// ---------------------------------------------------------------- bf16 weight prep
__global__ void wprep_k(const float* __restrict__ cw, const float* __restrict__ w1,
                        const float* __restrict__ w2,
                        short* __restrict__ wtc, short* __restrict__ wt1,
                        short* __restrict__ wt2) {
    int idx = blockIdx.x * 256 + threadIdx.x;
    if (idx >= WTOT_) return;
    int b = idx / SZB_;
    int rem = idx - b * SZB_;
    if (rem < SZ1_) {
        int n = rem / 192, k = rem - n * 192;
        int part = k >> 6, c = k & 63;
        const float* base = cw + (size_t)b * 3 * 64 * 128;
        float v;
        if (part == 0)      v = base[c * 128 + n] - base[16384 + c * 128 + n];
        else if (part == 1) v = base[8192 + c * 128 + n];
        else                v = 2.f * base[16384 + c * 128 + n];
        wtc[(size_t)b * SZ1_ + n * 192 + k] = (short)bfr(v);
    } else if (rem < SZ1_ + SZ2_) {
        int r2 = rem - SZ1_;
        int n = r2 >> 7, k = r2 & 127;
        float v = w1[(size_t)b * 16384 + k * 128 + n];
        wt1[(size_t)b * SZ2_ + n * 128 + k] = (short)bfr(v);
    } else {
        int r3 = rem - SZ1_ - SZ2_;
        int n = r3 >> 7, k = r3 & 127;
        float v = w2[(size_t)b * 8192 + k * 64 + n];
        wt2[(size_t)b * SZ3_ + n * 128 + k] = (short)bfr(v);
    }
}

// ---------------------------------------------------------------- transposes
__global__ void transpose_in_k(const float* __restrict__ x, float* __restrict__ h,
                               ushort* __restrict__ hb) {
    int idx = blockIdx.x * 256 + threadIdx.x;
    int c4 = idx & 15;
    int nb = idx >> 4;        // n*B + b
    int b  = nb & (B_ - 1);
    int n  = nb >> 4;
    const float4 v = *(const float4*)(x + ((size_t)b * N_ + n) * C_ + (c4 << 2));
    *(float4*)(h + (size_t)nb * C_ + (c4 << 2)) = v;
    uint2 p;
    p.x = pack_bf2(v.x, v.y);
    p.y = pack_bf2(v.z, v.w);
    *(uint2*)(hb + (size_t)nb * C_ + (c4 << 2)) = p;
}

__global__ void transpose_out_k(const float* __restrict__ h, float* __restrict__ out) {
    int idx = blockIdx.x * 256 + threadIdx.x;
    int c4 = idx & 15;
    int nb = idx >> 4;
    int b  = nb & (B_ - 1);
    int n  = nb >> 4;
    const float4 v = *(const float4*)(h + (size_t)nb * C_ + (c4 << 2));
    *(float4*)(out + ((size_t)b * N_ + n) * C_ + (c4 << 2)) = v;
}

// ---------------------------------------------------------------- SpMM, superphased
// r10: 8 superphases x 128 cols; lane16 gathers uint4 (16B). XCD-pinned 1:1
// (sph = blockIdx%8). r9 post-mortem: nontemporal metadata pushed it to HBM
// latency and REGRESSED (134->196us) => metadata is L2-hit and latency-critical.
// The residual stall is the loop-backedge wait on metadata issued only one
// iteration earlier (~140cy cover vs ~250-600cy latency). Fix: DEPTH-2 metadata
// pipeline (M_cur/M_mid/M_far named rotation) -> backedge consumes metadata
// issued two iterations (~2x VALU cover) earlier. Blocks 20000->10000 (prologue
// amortized), metadata re-reads 16x->8x. All loads/stores plain (r9 reverted).
__global__ __launch_bounds__(256) void spmm_ph_k(const ushort* __restrict__ in,
                                                 ushort* __restrict__ out,
                                                 const int* __restrict__ offs,
                                                 const ushort* __restrict__ esrc,
                                                 const float* __restrict__ eww,
                                                 const int* __restrict__ perm) {
    const int b     = blockIdx.x;
    const int sph   = b & (SPH_ - 1);           // == XCD (HW round-robin)
    const int chunk = b >> 3;                   // 0..1249
    const int g      = threadIdx.x >> 4;
    const int lane16 = threadIdx.x & 15;
    const int n = perm[chunk * NPB_ + g];
    const int s0 = offs[n], s1 = offs[n + 1];
    const ushort* inp = in + (size_t)sph * PC2_ + (lane16 << 3);

    f32x2 a0 = {0.f, 0.f}, a1 = {0.f, 0.f}, a2 = {0.f, 0.f}, a3 = {0.f, 0.f};
    if (s0 < s1) {
        // depth-2 metadata pipeline: cur (consumed now), mid (next iter),
        // far (loaded in-loop for iter+2). Reads past s1 stay inside EP_ pad.
        u16x4 sCur = *(const u16x4*)(esrc + s0);
        f32x4 wCur = *(const f32x4*)(eww + s0);
        u16x4 sMid = *(const u16x4*)(esrc + s0 + 4);
        f32x4 wMid = *(const f32x4*)(eww + s0 + 4);
        for (int i = s0; i < s1; i += 4) {
            u32x4 v0 = *(const u32x4*)(inp + ((u32)sCur.x << 10));
            u32x4 v1 = *(const u32x4*)(inp + ((u32)sCur.y << 10));
            u32x4 v2 = *(const u32x4*)(inp + ((u32)sCur.z << 10));
            u32x4 v3 = *(const u32x4*)(inp + ((u32)sCur.w << 10));
            u16x4 sFar = *(const u16x4*)(esrc + i + 8);
            f32x4 wFar = *(const f32x4*)(eww + i + 8);
            a0 += (f32x2){wCur.x, wCur.x} * bfpair(v0.x);
            a1 += (f32x2){wCur.x, wCur.x} * bfpair(v0.y);
            a2 += (f32x2){wCur.x, wCur.x} * bfpair(v0.z);
            a3 += (f32x2){wCur.x, wCur.x} * bfpair(v0.w);
            a0 += (f32x2){wCur.y, wCur.y} * bfpair(v1.x);
            a1 += (f32x2){wCur.y, wCur.y} * bfpair(v1.y);
            a2 += (f32x2){wCur.y, wCur.y} * bfpair(v1.z);
            a3 += (f32x2){wCur.y, wCur.y} * bfpair(v1.w);
            a0 += (f32x2){wCur.z, wCur.z} * bfpair(v2.x);
            a1 += (f32x2){wCur.z, wCur.z} * bfpair(v2.y);
            a2 += (f32x2){wCur.z, wCur.z} * bfpair(v2.z);
            a3 += (f32x2){wCur.z, wCur.z} * bfpair(v2.w);
            a0 += (f32x2){wCur.w, wCur.w} * bfpair(v3.x);
            a1 += (f32x2){wCur.w, wCur.w} * bfpair(v3.y);
            a2 += (f32x2){wCur.w, wCur.w} * bfpair(v3.z);
            a3 += (f32x2){wCur.w, wCur.w} * bfpair(v3.w);
            sCur = sMid; wCur = wMid;
            sMid = sFar; wMid = wFar;
        }
    }
    u32x4 p;
    p.x = pack_bf2(a0.x, a0.y);
    p.y = pack_bf2(a1.x, a1.y);
    p.z = pack_bf2(a2.x, a2.y);
    p.w = pack_bf2(a3.x, a3.y);
    *(u32x4*)(out + (size_t)n * ROW_ + (size_t)sph * PC2_ + (lane16 << 3)) = p;
}

// ---------------------------------------------------------------- MFMA MLP block
// Column-sliced wave partition (r6): each of the 4 waves owns 32/128 cols
// (16/64 for stage 3) across ALL 64 rows; weight fragments live in register
// arrays (batched loads). A-tile [64x192]=[hb|t1b|sb] reg-staged into LDS once;
// g1/g2 alias the same buffer between barriers. LDS 25600B, stride 200 shorts.
__global__ __launch_bounds__(256, 4) void mlp_mfma_k(
        float* __restrict__ h, ushort* __restrict__ hb,
        const ushort* __restrict__ t1b, const ushort* __restrict__ sb,
        const short* __restrict__ wtc, const short* __restrict__ wt1,
        const short* __restrict__ wt2,
        const float* __restrict__ cbias, const float* __restrict__ b1,
        const float* __restrict__ b2, const float* __restrict__ betap) {
    __shared__ __align__(16) short u[64 * LDP];

    const int tid  = threadIdx.x;
    const int wv   = tid >> 6;
    const int lane = tid & 63;
    const int m    = lane & 15;
    const int q    = lane >> 4;
    const int row0 = blockIdx.x * 64;
    const float sp    = __logf(1.f + __expf(betap[0]));
    const float inv11 = 1.0f / 1.1f;

    // ---- stage-1 weight fragments (12): cols n = wv*32 + t*16 + m, k = kb*32+q*8
    s16x8 wA[6][2];
#pragma unroll
    for (int kb = 0; kb < 6; ++kb)
#pragma unroll
        for (int t = 0; t < 2; ++t)
            wA[kb][t] = *(const s16x8*)(wtc + ((wv << 5) + (t << 4) + m) * 192
                                            + (kb << 5) + (q << 3));

    // ---- cooperative A-tile fill: [64 rows][192 cols] = [hb|t1b|sb], batched
    {
        const ushort* srcs[3] = { hb, t1b, sb };
        s16x8 tv[3][2];
#pragma unroll
        for (int s = 0; s < 3; ++s)
#pragma unroll
            for (int i = 0; i < 2; ++i) {
                int ck = tid + (i << 8);            // 0..511
                int r = ck >> 3, c8 = ck & 7;
                tv[s][i] = *(const s16x8*)(srcs[s] + (size_t)(row0 + r) * C_ + (c8 << 3));
            }
#pragma unroll
        for (int s = 0; s < 3; ++s)
#pragma unroll
            for (int i = 0; i < 2; ++i) {
                int ck = tid + (i << 8);
                int r = ck >> 3, c8 = ck & 7;
                *(s16x8*)(u + r * LDP + (s << 6) + (c8 << 3)) = tv[s][i];
            }
    }
    __syncthreads();

    // ---- stage 1: A(64x192) @ Wc^T-slice -> acc[rg][t] (64 rows x 32 cols/wave)
    f32x4 acc[4][2];
#pragma unroll
    for (int rg = 0; rg < 4; ++rg)
#pragma unroll
        for (int t = 0; t < 2; ++t) acc[rg][t] = (f32x4){0.f, 0.f, 0.f, 0.f};
#pragma unroll
    for (int kb = 0; kb < 6; ++kb)
#pragma unroll
        for (int rg = 0; rg < 4; ++rg) {
            s16x8 af = *(const s16x8*)(u + ((rg << 4) + m) * LDP + (kb << 5) + (q << 3));
            acc[rg][0] = __builtin_amdgcn_mfma_f32_16x16x32_bf16(af, wA[kb][0], acc[rg][0], 0, 0, 0);
            acc[rg][1] = __builtin_amdgcn_mfma_f32_16x16x32_bf16(af, wA[kb][1], acc[rg][1], 0, 0, 0);
        }
    __syncthreads();   // all waves done reading A-tile; u now becomes g1

    // stage-2 weight prefetch (overlaps epilogue-1 VALU; wA is dead now)
    s16x8 wB[4][2];
#pragma unroll
    for (int k4 = 0; k4 < 4; ++k4)
#pragma unroll
        for (int t = 0; t < 2; ++t)
            wB[k4][t] = *(const s16x8*)(wt1 + (((wv << 5) + (t << 4) + m) << 7)
                                            + (k4 << 5) + (q << 3));

    // ---- epilogue 1: bias + swish -> g1 (cols wv*32..wv*32+31, all 64 rows)
    {
        float cb0 = cbias[(wv << 5) + m];
        float cb1 = cbias[(wv << 5) + 16 + m];
#pragma unroll
        for (int rg = 0; rg < 4; ++rg)
#pragma unroll
            for (int t = 0; t < 2; ++t) {
                float bv = t ? cb1 : cb0;
#pragma unroll
                for (int r = 0; r < 4; ++r) {
                    float o = acc[rg][t][r] + bv;
                    float g = o * (1.f / (1.f + __expf(-o * sp))) * inv11;
                    u[((rg << 4) + (q << 2) + r) * LDP + (wv << 5) + (t << 4) + m] =
                        (short)bfr(g);
                }
            }
    }
    __syncthreads();

    // ---- stage 2: g1(64x128) @ w1^T-slice
    f32x4 acc2[4][2];
#pragma unroll
    for (int rg = 0; rg < 4; ++rg)
#pragma unroll
        for (int t = 0; t < 2; ++t) acc2[rg][t] = (f32x4){0.f, 0.f, 0.f, 0.f};
#pragma unroll
    for (int k4 = 0; k4 < 4; ++k4)
#pragma unroll
        for (int rg = 0; rg < 4; ++rg) {
            s16x8 af = *(const s16x8*)(u + ((rg << 4) + m) * LDP + (k4 << 5) + (q << 3));
            acc2[rg][0] = __builtin_amdgcn_mfma_f32_16x16x32_bf16(af, wB[k4][0], acc2[rg][0], 0, 0, 0);
            acc2[rg][1] = __builtin_amdgcn_mfma_f32_16x16x32_bf16(af, wB[k4][1], acc2[rg][1], 0, 0, 0);
        }
    __syncthreads();   // all waves done reading g1; u now becomes g2

    // stage-3 weight prefetch (overlaps epilogue-2 VALU)
    s16x8 wC[4];
#pragma unroll
    for (int k4 = 0; k4 < 4; ++k4)
        wC[k4] = *(const s16x8*)(wt2 + (((wv << 4) + m) << 7) + (k4 << 5) + (q << 3));

    // ---- epilogue 2: bias + swish -> g2
    {
        float b10 = b1[(wv << 5) + m];
        float b11 = b1[(wv << 5) + 16 + m];
#pragma unroll
        for (int rg = 0; rg < 4; ++rg)
#pragma unroll
            for (int t = 0; t < 2; ++t) {
                float bv = t ? b11 : b10;
#pragma unroll
                for (int r = 0; r < 4; ++r) {
                    float o = acc2[rg][t][r] + bv;
                    float g = o * (1.f / (1.f + __expf(-o * sp))) * inv11;
                    u[((rg << 4) + (q << 2) + r) * LDP + (wv << 5) + (t << 4) + m] =
                        (short)bfr(g);
                }
            }
    }
    __syncthreads();

    // ---- stage 3: g2(64x128) @ w2^T-slice -> 16 cols/wave
    f32x4 acc3[4];
#pragma unroll
    for (int rg = 0; rg < 4; ++rg) acc3[rg] = (f32x4){0.f, 0.f, 0.f, 0.f};
#pragma unroll
    for (int k4 = 0; k4 < 4; ++k4)
#pragma unroll
        for (int rg = 0; rg < 4; ++rg) {
            s16x8 af = *(const s16x8*)(u + ((rg << 4) + m) * LDP + (k4 << 5) + (q << 3));
            acc3[rg] = __builtin_amdgcn_mfma_f32_16x16x32_bf16(af, wC[k4], acc3[rg], 0, 0, 0);
        }

    // ---- epilogue 3: residual h += f (batched h loads), refresh hb
    {
        float b2v = b2[(wv << 4) + m];
        float hv[4][4];
#pragma unroll
        for (int rg = 0; rg < 4; ++rg)
#pragma unroll
            for (int r = 0; r < 4; ++r)
                hv[rg][r] = h[(size_t)(row0 + (rg << 4) + (q << 2) + r) * C_
                              + (wv << 4) + m];
#pragma unroll
        for (int rg = 0; rg < 4; ++rg)
#pragma unroll
            for (int r = 0; r < 4; ++r) {
                size_t eidx = (size_t)(row0 + (rg << 4) + (q << 2) + r) * C_
                              + (wv << 4) + m;
                float nv = hv[rg][r] + acc3[rg][r] + b2v;
                h[eidx]  = nv;
                hb[eidx] = (ushort)bfr(nv);
            }
    }
}

// ---------------------------------------------------------------- launch
extern "C" void kernel_launch(void* const* d_in, const int* in_sizes, int n_in,
                              void* d_out, int out_size, void* d_ws, size_t ws_size,
                              hipStream_t stream) {
    const float* x    = (const float*)d_in[0];
    const int*   ei   = (const int*)d_in[1];
    const float* ew   = (const float*)d_in[2];
    const float* cw   = (const float*)d_in[3];
    const float* cb   = (const float*)d_in[4];
    const float* beta = (const float*)d_in[5];
    const float* w1   = (const float*)d_in[6];
    const float* b1   = (const float*)d_in[7];
    const float* w2   = (const float*)d_in[8];
    const float* b2   = (const float*)d_in[9];
    float* out = (float*)d_out;

    char* ws = (char*)d_ws;
    float*  h_t  = (float*) (ws + OFF_H);
    ushort* hb   = (ushort*)(ws + OFF_HB);
    ushort* t1b  = (ushort*)(ws + OFF_T1B);
    ushort* sb   = (ushort*)(ws + OFF_SB);
    float*  deg  = (float*) (ws + OFF_DEG);
    int*    cnt  = (int*)   (ws + OFF_CNT);
    int*    offs = (int*)   (ws + OFF_OFFS);
    ushort* esrc = (ushort*)(ws + OFF_ESRC);
    float*  eww  = (float*) (ws + OFF_EW);
    int*    perm = (int*)   (ws + OFF_PERM);
    int*    hist = (int*)   (ws + OFF_HIST);
    int*    hoff = (int*)   (ws + OFF_HOFF);
    int*    hfil = (int*)   (ws + OFF_HFIL);
    short*  wtc  = (short*) (ws + OFF_WTC);
    short*  wt1  = (short*) (ws + OFF_WT1);
    short*  wt2  = (short*) (ws + OFF_WT2);

    const int* srcI = ei;
    const int* dstI = ei + E_;

    // graph prep
    hipMemsetAsync(deg, 0, (size_t)N_ * 4, stream);
    hipMemsetAsync(cnt, 0, (size_t)N_ * 4, stream);
    hipMemsetAsync(hist, 0, (size_t)NBIN_ * 4, stream);
    hipMemsetAsync(hfil, 0, (size_t)NBIN_ * 4, stream);
    hipMemsetAsync(esrc, 0, (size_t)EP_ * 2, stream);   // pad entries: src=0
    hipMemsetAsync(eww,  0, (size_t)EP_ * 4, stream);   // pad entries: w=0
    deg_cnt_k<<<(E_ + 255) / 256, 256, 0, stream>>>(srcI, dstI, ew, deg, cnt);
    dinv_k<<<(N_ + 255) / 256, 256, 0, stream>>>(deg);
    scan_k<<<1, 1024, 0, stream>>>(cnt, offs);
    hist_k<<<(N_ + 255) / 256, 256, 0, stream>>>(cnt, hist);
    hscan_k<<<1, NBIN_, 0, stream>>>(hist, hoff);
    permscatter_k<<<(N_ + 255) / 256, 256, 0, stream>>>(cnt, hoff, hfil, perm);
    hipMemsetAsync(cnt, 0, (size_t)N_ * 4, stream);
    scatter_k<<<(E_ + 255) / 256, 256, 0, stream>>>(srcI, dstI, ew, deg, offs, cnt,
                                                    esrc, eww);

    // bf16 weights
    wprep_k<<<(WTOT_ + 255) / 256, 256, 0, stream>>>(cw, w1, w2, wtc, wt1, wt2);

    // x -> [N,B,C] (fp32 + bf16 image)
    transpose_in_k<<<(N_ * B_ * 16) / 256, 256, 0, stream>>>(x, h_t, hb);

    for (int b = 0; b < NB_; ++b) {
        spmm_ph_k<<<SPH_ * NCHK_, 256, 0, stream>>>(hb, t1b, offs, esrc, eww, perm);
        spmm_ph_k<<<SPH_ * NCHK_, 256, 0, stream>>>(t1b, sb, offs, esrc, eww, perm);
        mlp_mfma_k<<<NR_ / 64, 256, 0, stream>>>(h_t, hb, t1b, sb,
                                                 wtc + (size_t)b * SZ1_,
                                                 wt1 + (size_t)b * SZ2_,
                                                 wt2 + (size_t)b * SZ3_,
                                                 cb + (size_t)b * DIM_,
                                                 b1 + (size_t)b * DIM_,
                                                 b2 + (size_t)b * C_,
                                                 beta + b);
    }

    // [N,B,C] -> out
    transpose_out_k<<<(N_ * B_ * 16) / 256, 256, 0, stream>>>(h_t, out);
}

// Round 6
// 1174.280 us; speedup vs baseline: 1.5447x; 1.0868x over previous
//
#include <hip/hip_runtime.h>

// ---------------------------------------------------------------- constants
namespace {
constexpr int   B_   = 16;
constexpr int   N_   = 20000;
constexpr int   C_   = 64;
constexpr int   DIM_ = 128;
constexpr int   E_   = 640000;
constexpr int   NB_  = 3;
constexpr int   ROW_ = B_ * C_;      // 1024 elements per node row in [N,B,C]
constexpr int   NR_  = N_ * B_;      // 320000 rows of C elements

constexpr int   LDP  = 200;          // LDS row stride (shorts) for MLP kernel

// SpMM phase blocking (r11 = r7 geometry + r10 issue efficiency):
// 16 phases x 64 cols (128B slice/node); slice = N*128B = 2.56MB -> fits 4MB
// XCD L2. 8 lanes per node, each lane gathers uint4 (16B). 32 nodes/block.
constexpr int   PH_   = 16;          // phases
constexpr int   PCOL_ = ROW_ / PH_;  // 64 cols per phase
constexpr int   NPB_  = 32;          // nodes per block (8 lanes each)
constexpr int   NCHK_ = N_ / NPB_;   // 625 chunks per phase
constexpr int   NBIN_ = 1024;        // degree-sort bins
constexpr int   NXCD_ = 8;           // XCDs; blockIdx % 8 -> XCD (round-robin)
constexpr int   EP_   = E_ + 7 * N_ + 64;   // padded edge capacity (lists %8)

// bf16 weight region sizes (elements)
constexpr int   SZ1_ = 128 * 192;    // Wc^T  per block
constexpr int   SZ2_ = 128 * 128;    // w1^T  per block
constexpr int   SZ3_ = 64 * 128;     // w2^T  per block
constexpr int   SZB_ = SZ1_ + SZ2_ + SZ3_;
constexpr int   WTOT_ = NB_ * SZB_;

// workspace layout (bytes)
constexpr size_t SZH_  = (size_t)N_ * ROW_ * sizeof(float);   // fp32 h
constexpr size_t SZHB_ = (size_t)N_ * ROW_ * 2;               // bf16 row image
constexpr size_t OFF_H    = 0;
constexpr size_t OFF_HB   = SZH_;
constexpr size_t OFF_T1B  = OFF_HB  + SZHB_;
constexpr size_t OFF_SB   = OFF_T1B + SZHB_;
constexpr size_t OFF_DEG  = OFF_SB  + SZHB_;
constexpr size_t OFF_CNT  = OFF_DEG + (size_t)N_ * 4;
constexpr size_t OFF_OFFS = OFF_CNT + (size_t)N_ * 4;
constexpr size_t OFF_CV   = ((OFF_OFFS + (size_t)(N_ + 1) * 4 + 255) / 256) * 256;
// esrc (u16[EP_]) + eww (f32[EP_]) live inside the old 8B-cv footprint
constexpr size_t OFF_ESRC = OFF_CV;
constexpr size_t OFF_EW   = ((OFF_ESRC + (size_t)EP_ * 2 + 255) / 256) * 256;
static_assert(OFF_EW + (size_t)EP_ * 4 <= OFF_CV + (size_t)E_ * 8, "cv region overflow");
constexpr size_t OFF_PERM = OFF_CV   + (size_t)E_ * 8;
constexpr size_t OFF_HIST = OFF_PERM + (size_t)N_ * 4;
constexpr size_t OFF_HOFF = OFF_HIST + (size_t)NBIN_ * 4;
constexpr size_t OFF_HFIL = OFF_HOFF + (size_t)NBIN_ * 4;
constexpr size_t OFF_WTC  = OFF_HFIL + (size_t)NBIN_ * 4;
constexpr size_t OFF_WT1  = OFF_WTC + (size_t)NB_ * SZ1_ * 2;
constexpr size_t OFF_WT2  = OFF_WT1 + (size_t)NB_ * SZ2_ * 2;
// total ~210 MB
} // namespace

typedef short s16x8 __attribute__((ext_vector_type(8)));
typedef float f32x4 __attribute__((ext_vector_type(4)));
typedef float f32x2 __attribute__((ext_vector_type(2)));
typedef unsigned int u32;
typedef u32   u32x4 __attribute__((ext_vector_type(4)));
typedef u32   u32x2 __attribute__((ext_vector_type(2)));
typedef unsigned short u16;
typedef u16   u16x8 __attribute__((ext_vector_type(8)));

__device__ __forceinline__ u32 bfr(float x) {
    u32 u = __float_as_uint(x);
    return (u + 0x7FFFu + ((u >> 16) & 1u)) >> 16;
}
__device__ __forceinline__ u32 pack_bf2(float x, float y) {
    return bfr(x) | (bfr(y) << 16);
}
// {lo,hi} bf16 pair -> f32x2 (feeds v_pk_fma_f32)
__device__ __forceinline__ f32x2 bfpair(u32 u) {
    u32x2 r;
    r.x = u << 16;
    r.y = u & 0xFFFF0000u;
    return __builtin_bit_cast(f32x2, r);
}

// ---------------------------------------------------------------- graph prep
__global__ void deg_cnt_k(const int* __restrict__ src, const int* __restrict__ dst,
                          const float* __restrict__ ew,
                          float* __restrict__ deg, int* __restrict__ cnt) {
    int e = blockIdx.x * 256 + threadIdx.x;
    if (e < E_) {
        atomicAdd(deg + src[e], ew[e]);
        atomicAdd(cnt + dst[e], 1);
    }
}

__global__ void dinv_k(float* __restrict__ deg) {
    int i = blockIdx.x * 256 + threadIdx.x;
    if (i < N_) {
        float d = deg[i];
        deg[i] = (d > 0.f) ? rsqrtf(fmaxf(d, 1e-12f)) : 0.f;
    }
}

// exclusive scan of per-node counts PADDED to multiples of 8 (branch-free spmm)
__global__ __launch_bounds__(1024) void scan_k(const int* __restrict__ cnt,
                                               int* __restrict__ offs) {
    __shared__ int sums[1024];
    const int tid = threadIdx.x;
    constexpr int CH = (N_ + 1023) / 1024;   // 20
    const int base = tid * CH;
    int local = 0;
    for (int j = 0; j < CH; ++j) {
        int i = base + j;
        if (i < N_) local += (cnt[i] + 7) & ~7;
    }
    sums[tid] = local;
    __syncthreads();
    for (int off = 1; off < 1024; off <<= 1) {
        int v = sums[tid];
        int u = (tid >= off) ? sums[tid - off] : 0;
        __syncthreads();
        sums[tid] = v + u;
        __syncthreads();
    }
    int run = (tid > 0) ? sums[tid - 1] : 0;
    for (int j = 0; j < CH; ++j) {
        int i = base + j;
        if (i < N_) { offs[i] = run; run += (cnt[i] + 7) & ~7; }
    }
    if (tid == 1023) offs[N_] = sums[1023];
}

// degree histogram / scan / perm-scatter (degree-sorted node order)
__global__ void hist_k(const int* __restrict__ cnt, int* __restrict__ hist) {
    int i = blockIdx.x * 256 + threadIdx.x;
    if (i < N_) atomicAdd(hist + min(cnt[i], NBIN_ - 1), 1);
}

__global__ __launch_bounds__(1024) void hscan_k(const int* __restrict__ hist,
                                                int* __restrict__ hoffs) {
    __shared__ int s[NBIN_];
    int t = threadIdx.x;
    s[t] = hist[t];
    __syncthreads();
    for (int off = 1; off < NBIN_; off <<= 1) {
        int v = s[t];
        int u = (t >= off) ? s[t - off] : 0;
        __syncthreads();
        s[t] = v + u;
        __syncthreads();
    }
    hoffs[t] = (t > 0) ? s[t - 1] : 0;
}

__global__ void permscatter_k(const int* __restrict__ cnt, const int* __restrict__ hoffs,
                              int* __restrict__ hfill, int* __restrict__ perm) {
    int i = blockIdx.x * 256 + threadIdx.x;
    if (i < N_) {
        int b = min(cnt[i], NBIN_ - 1);
        int pos = hoffs[b] + atomicAdd(hfill + b, 1);
        perm[pos] = i;
    }
}

// split edge store: u16 src + f32 weight (6B/edge). pads stay 0 (memset).
__global__ void scatter_k(const int* __restrict__ src, const int* __restrict__ dst,
                          const float* __restrict__ ew, const float* __restrict__ dinv,
                          const int* __restrict__ offs, int* __restrict__ fill,
                          ushort* __restrict__ esrc, float* __restrict__ eww) {
    int e = blockIdx.x * 256 + threadIdx.x;
    if (e < E_) {
        int s = src[e], d = dst[e];
        int pos = offs[d] + atomicAdd(fill + d, 1);
        float w = -dinv[s] * ew[e] * dinv[d];
        esrc[pos] = (ushort)s;
        eww[pos]  = w;
    }
}

// ---------------------------------------------------------------- bf16 weight prep
__global__ void wprep_k(const float* __restrict__ cw, const float* __restrict__ w1,
                        const float* __restrict__ w2,
                        short* __restrict__ wtc, short* __restrict__ wt1,
                        short* __restrict__ wt2) {
    int idx = blockIdx.x * 256 + threadIdx.x;
    if (idx >= WTOT_) return;
    int b = idx / SZB_;
    int rem = idx - b * SZB_;
    if (rem < SZ1_) {
        int n = rem / 192, k = rem - n * 192;
        int part = k >> 6, c = k & 63;
        const float* base = cw + (size_t)b * 3 * 64 * 128;
        float v;
        if (part == 0)      v = base[c * 128 + n] - base[16384 + c * 128 + n];
        else if (part == 1) v = base[8192 + c * 128 + n];
        else                v = 2.f * base[16384 + c * 128 + n];
        wtc[(size_t)b * SZ1_ + n * 192 + k] = (short)bfr(v);
    } else if (rem < SZ1_ + SZ2_) {
        int r2 = rem - SZ1_;
        int n = r2 >> 7, k = r2 & 127;
        float v = w1[(size_t)b * 16384 + k * 128 + n];
        wt1[(size_t)b * SZ2_ + n * 128 + k] = (short)bfr(v);
    } else {
        int r3 = rem - SZ1_ - SZ2_;
        int n = r3 >> 7, k = r3 & 127;
        float v = w2[(size_t)b * 8192 + k * 64 + n];
        wt2[(size_t)b * SZ3_ + n * 128 + k] = (short)bfr(v);
    }
}

// ---------------------------------------------------------------- transposes
__global__ void transpose_in_k(const float* __restrict__ x, float* __restrict__ h,
                               ushort* __restrict__ hb) {
    int idx = blockIdx.x * 256 + threadIdx.x;
    int c4 = idx & 15;
    int nb = idx >> 4;        // n*B + b
    int b  = nb & (B_ - 1);
    int n  = nb >> 4;
    const float4 v = *(const float4*)(x + ((size_t)b * N_ + n) * C_ + (c4 << 2));
    *(float4*)(h + (size_t)nb * C_ + (c4 << 2)) = v;
    uint2 p;
    p.x = pack_bf2(v.x, v.y);
    p.y = pack_bf2(v.z, v.w);
    *(uint2*)(hb + (size_t)nb * C_ + (c4 << 2)) = p;
}

__global__ void transpose_out_k(const float* __restrict__ h, float* __restrict__ out) {
    int idx = blockIdx.x * 256 + threadIdx.x;
    int c4 = idx & 15;
    int nb = idx >> 4;
    int b  = nb & (B_ - 1);
    int n  = nb >> 4;
    const float4 v = *(const float4*)(h + (size_t)nb * C_ + (c4 << 2));
    *(float4*)(out + ((size_t)b * N_ + n) * C_ + (c4 << 2)) = v;
}

// ---------------------------------------------------------------- SpMM
// r11 = r7 L2 geometry + r10 issue width. 16 phases x 64 cols: gather slice
// N*128B = 2.56MB fits one XCD L2 (r10's 5.12MB slice did NOT -> FETCH 290MB,
// gathers at L3 latency). XCD-pinned: XCD x runs phases {2x,2x+1} slot-ordered.
// 8 lanes/node x uint4 = the node's full 128B phase slice, coalesced. 8 edges
// per iter (8 gathers in flight), depth-2 metadata pipeline (named rotation,
// consumed ~2 iters = ~500cy after issue). Edge lists padded %8 (pads w=0).
__global__ __launch_bounds__(256) void spmm_ph_k(const ushort* __restrict__ in,
                                                 ushort* __restrict__ out,
                                                 const int* __restrict__ offs,
                                                 const ushort* __restrict__ esrc,
                                                 const float* __restrict__ eww,
                                                 const int* __restrict__ perm) {
    const int b     = blockIdx.x;
    const int xcd   = b & (NXCD_ - 1);
    const int slot  = b >> 3;                   // 0..1249
    const int half  = (slot >= NCHK_) ? 1 : 0;
    const int ph    = (xcd << 1) | half;
    const int chunk = slot - (half ? NCHK_ : 0);
    const int g     = threadIdx.x >> 3;         // 0..31 node group
    const int lane8 = threadIdx.x & 7;
    const int n = perm[chunk * NPB_ + g];
    const int s0 = offs[n], s1 = offs[n + 1];
    const ushort* inp = in + (size_t)ph * PCOL_ + (lane8 << 3);

    f32x2 a0 = {0.f, 0.f}, a1 = {0.f, 0.f}, a2 = {0.f, 0.f}, a3 = {0.f, 0.f};
    if (s0 < s1) {
        // depth-2 metadata pipeline (reads past s1 stay inside EP_ pad)
        u16x8 sCur = *(const u16x8*)(esrc + s0);
        f32x4 wCurA = *(const f32x4*)(eww + s0);
        f32x4 wCurB = *(const f32x4*)(eww + s0 + 4);
        u16x8 sMid = *(const u16x8*)(esrc + s0 + 8);
        f32x4 wMidA = *(const f32x4*)(eww + s0 + 8);
        f32x4 wMidB = *(const f32x4*)(eww + s0 + 12);
        for (int i = s0; i < s1; i += 8) {
            u32x4 v0 = *(const u32x4*)(inp + ((u32)sCur[0] << 10));
            u32x4 v1 = *(const u32x4*)(inp + ((u32)sCur[1] << 10));
            u32x4 v2 = *(const u32x4*)(inp + ((u32)sCur[2] << 10));
            u32x4 v3 = *(const u32x4*)(inp + ((u32)sCur[3] << 10));
            u32x4 v4 = *(const u32x4*)(inp + ((u32)sCur[4] << 10));
            u32x4 v5 = *(const u32x4*)(inp + ((u32)sCur[5] << 10));
            u32x4 v6 = *(const u32x4*)(inp + ((u32)sCur[6] << 10));
            u32x4 v7 = *(const u32x4*)(inp + ((u32)sCur[7] << 10));
            u16x8 sFar = *(const u16x8*)(esrc + i + 16);
            f32x4 wFarA = *(const f32x4*)(eww + i + 16);
            f32x4 wFarB = *(const f32x4*)(eww + i + 20);
            a0 += (f32x2){wCurA.x, wCurA.x} * bfpair(v0.x);
            a1 += (f32x2){wCurA.x, wCurA.x} * bfpair(v0.y);
            a2 += (f32x2){wCurA.x, wCurA.x} * bfpair(v0.z);
            a3 += (f32x2){wCurA.x, wCurA.x} * bfpair(v0.w);
            a0 += (f32x2){wCurA.y, wCurA.y} * bfpair(v1.x);
            a1 += (f32x2){wCurA.y, wCurA.y} * bfpair(v1.y);
            a2 += (f32x2){wCurA.y, wCurA.y} * bfpair(v1.z);
            a3 += (f32x2){wCurA.y, wCurA.y} * bfpair(v1.w);
            a0 += (f32x2){wCurA.z, wCurA.z} * bfpair(v2.x);
            a1 += (f32x2){wCurA.z, wCurA.z} * bfpair(v2.y);
            a2 += (f32x2){wCurA.z, wCurA.z} * bfpair(v2.z);
            a3 += (f32x2){wCurA.z, wCurA.z} * bfpair(v2.w);
            a0 += (f32x2){wCurA.w, wCurA.w} * bfpair(v3.x);
            a1 += (f32x2){wCurA.w, wCurA.w} * bfpair(v3.y);
            a2 += (f32x2){wCurA.w, wCurA.w} * bfpair(v3.z);
            a3 += (f32x2){wCurA.w, wCurA.w} * bfpair(v3.w);
            a0 += (f32x2){wCurB.x, wCurB.x} * bfpair(v4.x);
            a1 += (f32x2){wCurB.x, wCurB.x} * bfpair(v4.y);
            a2 += (f32x2){wCurB.x, wCurB.x} * bfpair(v4.z);
            a3 += (f32x2){wCurB.x, wCurB.x} * bfpair(v4.w);
            a0 += (f32x2){wCurB.y, wCurB.y} * bfpair(v5.x);
            a1 += (f32x2){wCurB.y, wCurB.y} * bfpair(v5.y);
            a2 += (f32x2){wCurB.y, wCurB.y} * bfpair(v5.z);
            a3 += (f32x2){wCurB.y, wCurB.y} * bfpair(v5.w);
            a0 += (f32x2){wCurB.z, wCurB.z} * bfpair(v6.x);
            a1 += (f32x2){wCurB.z, wCurB.z} * bfpair(v6.y);
            a2 += (f32x2){wCurB.z, wCurB.z} * bfpair(v6.z);
            a3 += (f32x2){wCurB.z, wCurB.z} * bfpair(v6.w);
            a0 += (f32x2){wCurB.w, wCurB.w} * bfpair(v7.x);
            a1 += (f32x2){wCurB.w, wCurB.w} * bfpair(v7.y);
            a2 += (f32x2){wCurB.w, wCurB.w} * bfpair(v7.z);
            a3 += (f32x2){wCurB.w, wCurB.w} * bfpair(v7.w);
            sCur = sMid; wCurA = wMidA; wCurB = wMidB;
            sMid = sFar; wMidA = wFarA; wMidB = wFarB;
        }
    }
    u32x4 p;
    p.x = pack_bf2(a0.x, a0.y);
    p.y = pack_bf2(a1.x, a1.y);
    p.z = pack_bf2(a2.x, a2.y);
    p.w = pack_bf2(a3.x, a3.y);
    *(u32x4*)(out + (size_t)n * ROW_ + (size_t)ph * PCOL_ + (lane8 << 3)) = p;
}

// ---------------------------------------------------------------- MFMA MLP block
// Column-sliced wave partition (r6): each of the 4 waves owns 32/128 cols
// (16/64 for stage 3) across ALL 64 rows; weight fragments live in register
// arrays (batched loads). A-tile [64x192]=[hb|t1b|sb] reg-staged into LDS once;
// g1/g2 alias the same buffer between barriers. LDS 25600B, stride 200 shorts.
__global__ __launch_bounds__(256, 4) void mlp_mfma_k(
        float* __restrict__ h, ushort* __restrict__ hb,
        const ushort* __restrict__ t1b, const ushort* __restrict__ sb,
        const short* __restrict__ wtc, const short* __restrict__ wt1,
        const short* __restrict__ wt2,
        const float* __restrict__ cbias, const float* __restrict__ b1,
        const float* __restrict__ b2, const float* __restrict__ betap) {
    __shared__ __align__(16) short u[64 * LDP];

    const int tid  = threadIdx.x;
    const int wv   = tid >> 6;
    const int lane = tid & 63;
    const int m    = lane & 15;
    const int q    = lane >> 4;
    const int row0 = blockIdx.x * 64;
    const float sp    = __logf(1.f + __expf(betap[0]));
    const float inv11 = 1.0f / 1.1f;

    // ---- stage-1 weight fragments (12): cols n = wv*32 + t*16 + m, k = kb*32+q*8
    s16x8 wA[6][2];
#pragma unroll
    for (int kb = 0; kb < 6; ++kb)
#pragma unroll
        for (int t = 0; t < 2; ++t)
            wA[kb][t] = *(const s16x8*)(wtc + ((wv << 5) + (t << 4) + m) * 192
                                            + (kb << 5) + (q << 3));

    // ---- cooperative A-tile fill: [64 rows][192 cols] = [hb|t1b|sb], batched
    {
        const ushort* srcs[3] = { hb, t1b, sb };
        s16x8 tv[3][2];
#pragma unroll
        for (int s = 0; s < 3; ++s)
#pragma unroll
            for (int i = 0; i < 2; ++i) {
                int ck = tid + (i << 8);            // 0..511
                int r = ck >> 3, c8 = ck & 7;
                tv[s][i] = *(const s16x8*)(srcs[s] + (size_t)(row0 + r) * C_ + (c8 << 3));
            }
#pragma unroll
        for (int s = 0; s < 3; ++s)
#pragma unroll
            for (int i = 0; i < 2; ++i) {
                int ck = tid + (i << 8);
                int r = ck >> 3, c8 = ck & 7;
                *(s16x8*)(u + r * LDP + (s << 6) + (c8 << 3)) = tv[s][i];
            }
    }
    __syncthreads();

    // ---- stage 1: A(64x192) @ Wc^T-slice -> acc[rg][t] (64 rows x 32 cols/wave)
    f32x4 acc[4][2];
#pragma unroll
    for (int rg = 0; rg < 4; ++rg)
#pragma unroll
        for (int t = 0; t < 2; ++t) acc[rg][t] = (f32x4){0.f, 0.f, 0.f, 0.f};
#pragma unroll
    for (int kb = 0; kb < 6; ++kb)
#pragma unroll
        for (int rg = 0; rg < 4; ++rg) {
            s16x8 af = *(const s16x8*)(u + ((rg << 4) + m) * LDP + (kb << 5) + (q << 3));
            acc[rg][0] = __builtin_amdgcn_mfma_f32_16x16x32_bf16(af, wA[kb][0], acc[rg][0], 0, 0, 0);
            acc[rg][1] = __builtin_amdgcn_mfma_f32_16x16x32_bf16(af, wA[kb][1], acc[rg][1], 0, 0, 0);
        }
    __syncthreads();   // all waves done reading A-tile; u now becomes g1

    // stage-2 weight prefetch (overlaps epilogue-1 VALU; wA is dead now)
    s16x8 wB[4][2];
#pragma unroll
    for (int k4 = 0; k4 < 4; ++k4)
#pragma unroll
        for (int t = 0; t < 2; ++t)
            wB[k4][t] = *(const s16x8*)(wt1 + (((wv << 5) + (t << 4) + m) << 7)
                                            + (k4 << 5) + (q << 3));

    // ---- epilogue 1: bias + swish -> g1 (cols wv*32..wv*32+31, all 64 rows)
    {
        float cb0 = cbias[(wv << 5) + m];
        float cb1 = cbias[(wv << 5) + 16 + m];
#pragma unroll
        for (int rg = 0; rg < 4; ++rg)
#pragma unroll
            for (int t = 0; t < 2; ++t) {
                float bv = t ? cb1 : cb0;
#pragma unroll
                for (int r = 0; r < 4; ++r) {
                    float o = acc[rg][t][r] + bv;
                    float g = o * (1.f / (1.f + __expf(-o * sp))) * inv11;
                    u[((rg << 4) + (q << 2) + r) * LDP + (wv << 5) + (t << 4) + m] =
                        (short)bfr(g);
                }
            }
    }
    __syncthreads();

    // ---- stage 2: g1(64x128) @ w1^T-slice
    f32x4 acc2[4][2];
#pragma unroll
    for (int rg = 0; rg < 4; ++rg)
#pragma unroll
        for (int t = 0; t < 2; ++t) acc2[rg][t] = (f32x4){0.f, 0.f, 0.f, 0.f};
#pragma unroll
    for (int k4 = 0; k4 < 4; ++k4)
#pragma unroll
        for (int rg = 0; rg < 4; ++rg) {
            s16x8 af = *(const s16x8*)(u + ((rg << 4) + m) * LDP + (k4 << 5) + (q << 3));
            acc2[rg][0] = __builtin_amdgcn_mfma_f32_16x16x32_bf16(af, wB[k4][0], acc2[rg][0], 0, 0, 0);
            acc2[rg][1] = __builtin_amdgcn_mfma_f32_16x16x32_bf16(af, wB[k4][1], acc2[rg][1], 0, 0, 0);
        }
    __syncthreads();   // all waves done reading g1; u now becomes g2

    // stage-3 weight prefetch (overlaps epilogue-2 VALU)
    s16x8 wC[4];
#pragma unroll
    for (int k4 = 0; k4 < 4; ++k4)
        wC[k4] = *(const s16x8*)(wt2 + (((wv << 4) + m) << 7) + (k4 << 5) + (q << 3));

    // ---- epilogue 2: bias + swish -> g2
    {
        float b10 = b1[(wv << 5) + m];
        float b11 = b1[(wv << 5) + 16 + m];
#pragma unroll
        for (int rg = 0; rg < 4; ++rg)
#pragma unroll
            for (int t = 0; t < 2; ++t) {
                float bv = t ? b11 : b10;
#pragma unroll
                for (int r = 0; r < 4; ++r) {
                    float o = acc2[rg][t][r] + bv;
                    float g = o * (1.f / (1.f + __expf(-o * sp))) * inv11;
                    u[((rg << 4) + (q << 2) + r) * LDP + (wv << 5) + (t << 4) + m] =
                        (short)bfr(g);
                }
            }
    }
    __syncthreads();

    // ---- stage 3: g2(64x128) @ w2^T-slice -> 16 cols/wave
    f32x4 acc3[4];
#pragma unroll
    for (int rg = 0; rg < 4; ++rg) acc3[rg] = (f32x4){0.f, 0.f, 0.f, 0.f};
#pragma unroll
    for (int k4 = 0; k4 < 4; ++k4)
#pragma unroll
        for (int rg = 0; rg < 4; ++rg) {
            s16x8 af = *(const s16x8*)(u + ((rg << 4) + m) * LDP + (k4 << 5) + (q << 3));
            acc3[rg] = __builtin_amdgcn_mfma_f32_16x16x32_bf16(af, wC[k4], acc3[rg], 0, 0, 0);
        }

    // ---- epilogue 3: residual h += f (batched h loads), refresh hb
    {
        float b2v = b2[(wv << 4) + m];
        float hv[4][4];
#pragma unroll
        for (int rg = 0; rg < 4; ++rg)
#pragma unroll
            for (int r = 0; r < 4; ++r)
                hv[rg][r] = h[(size_t)(row0 + (rg << 4) + (q << 2) + r) * C_
                              + (wv << 4) + m];
#pragma unroll
        for (int rg = 0; rg < 4; ++rg)
#pragma unroll
            for (int r = 0; r < 4; ++r) {
                size_t eidx = (size_t)(row0 + (rg << 4) + (q << 2) + r) * C_
                              + (wv << 4) + m;
                float nv = hv[rg][r] + acc3[rg][r] + b2v;
                h[eidx]  = nv;
                hb[eidx] = (ushort)bfr(nv);
            }
    }
}

// ---------------------------------------------------------------- launch
extern "C" void kernel_launch(void* const* d_in, const int* in_sizes, int n_in,
                              void* d_out, int out_size, void* d_ws, size_t ws_size,
                              hipStream_t stream) {
    const float* x    = (const float*)d_in[0];
    const int*   ei   = (const int*)d_in[1];
    const float* ew   = (const float*)d_in[2];
    const float* cw   = (const float*)d_in[3];
    const float* cb   = (const float*)d_in[4];
    const float* beta = (const float*)d_in[5];
    const float* w1   = (const float*)d_in[6];
    const float* b1   = (const float*)d_in[7];
    const float* w2   = (const float*)d_in[8];
    const float* b2   = (const float*)d_in[9];
    float* out = (float*)d_out;

    char* ws = (char*)d_ws;
    float*  h_t  = (float*) (ws + OFF_H);
    ushort* hb   = (ushort*)(ws + OFF_HB);
    ushort* t1b  = (ushort*)(ws + OFF_T1B);
    ushort* sb   = (ushort*)(ws + OFF_SB);
    float*  deg  = (float*) (ws + OFF_DEG);
    int*    cnt  = (int*)   (ws + OFF_CNT);
    int*    offs = (int*)   (ws + OFF_OFFS);
    ushort* esrc = (ushort*)(ws + OFF_ESRC);
    float*  eww  = (float*) (ws + OFF_EW);
    int*    perm = (int*)   (ws + OFF_PERM);
    int*    hist = (int*)   (ws + OFF_HIST);
    int*    hoff = (int*)   (ws + OFF_HOFF);
    int*    hfil = (int*)   (ws + OFF_HFIL);
    short*  wtc  = (short*) (ws + OFF_WTC);
    short*  wt1  = (short*) (ws + OFF_WT1);
    short*  wt2  = (short*) (ws + OFF_WT2);

    const int* srcI = ei;
    const int* dstI = ei + E_;

    // graph prep
    hipMemsetAsync(deg, 0, (size_t)N_ * 4, stream);
    hipMemsetAsync(cnt, 0, (size_t)N_ * 4, stream);
    hipMemsetAsync(hist, 0, (size_t)NBIN_ * 4, stream);
    hipMemsetAsync(hfil, 0, (size_t)NBIN_ * 4, stream);
    hipMemsetAsync(esrc, 0, (size_t)EP_ * 2, stream);   // pad entries: src=0
    hipMemsetAsync(eww,  0, (size_t)EP_ * 4, stream);   // pad entries: w=0
    deg_cnt_k<<<(E_ + 255) / 256, 256, 0, stream>>>(srcI, dstI, ew, deg, cnt);
    dinv_k<<<(N_ + 255) / 256, 256, 0, stream>>>(deg);
    scan_k<<<1, 1024, 0, stream>>>(cnt, offs);
    hist_k<<<(N_ + 255) / 256, 256, 0, stream>>>(cnt, hist);
    hscan_k<<<1, NBIN_, 0, stream>>>(hist, hoff);
    permscatter_k<<<(N_ + 255) / 256, 256, 0, stream>>>(cnt, hoff, hfil, perm);
    hipMemsetAsync(cnt, 0, (size_t)N_ * 4, stream);
    scatter_k<<<(E_ + 255) / 256, 256, 0, stream>>>(srcI, dstI, ew, deg, offs, cnt,
                                                    esrc, eww);

    // bf16 weights
    wprep_k<<<(WTOT_ + 255) / 256, 256, 0, stream>>>(cw, w1, w2, wtc, wt1, wt2);

    // x -> [N,B,C] (fp32 + bf16 image)
    transpose_in_k<<<(N_ * B_ * 16) / 256, 256, 0, stream>>>(x, h_t, hb);

    for (int b = 0; b < NB_; ++b) {
        spmm_ph_k<<<PH_ * NCHK_, 256, 0, stream>>>(hb, t1b, offs, esrc, eww, perm);
        spmm_ph_k<<<PH_ * NCHK_, 256, 0, stream>>>(t1b, sb, offs, esrc, eww, perm);
        mlp_mfma_k<<<NR_ / 64, 256, 0, stream>>>(h_t, hb, t1b, sb,
                                                 wtc + (size_t)b * SZ1_,
                                                 wt1 + (size_t)b * SZ2_,
                                                 wt2 + (size_t)b * SZ3_,
                                                 cb + (size_t)b * DIM_,
                                                 b1 + (size_t)b * DIM_,
                                                 b2 + (size_t)b * C_,
                                                 beta + b);
    }

    // [N,B,C] -> out
    transpose_out_k<<<(N_ * B_ * 16) / 256, 256, 0, stream>>>(h_t, out);
}

// Round 7
// 1128.924 us; speedup vs baseline: 1.6068x; 1.0402x over previous
//
#include <hip/hip_runtime.h>

// ---------------------------------------------------------------- constants
namespace {
constexpr int   B_   = 16;
constexpr int   N_   = 20000;
constexpr int   C_   = 64;
constexpr int   DIM_ = 128;
constexpr int   E_   = 640000;
constexpr int   NB_  = 3;
constexpr int   ROW_ = B_ * C_;      // 1024 elements per node row in [N,B,C]
constexpr int   NR_  = N_ * B_;      // 320000 rows of C elements

constexpr int   LDP  = 200;          // LDS row stride (shorts) for MLP kernel

// SpMM phase blocking (r11 = r7 geometry + r10 issue efficiency):
// 16 phases x 64 cols (128B slice/node); slice = N*128B = 2.56MB -> fits 4MB
// XCD L2. 8 lanes per node, each lane gathers uint4 (16B). 32 nodes/block.
constexpr int   PH_   = 16;          // phases
constexpr int   PCOL_ = ROW_ / PH_;  // 64 cols per phase
constexpr int   NPB_  = 32;          // nodes per block (8 lanes each)
constexpr int   NCHK_ = N_ / NPB_;   // 625 chunks per phase
constexpr int   NBIN_ = 1024;        // degree-sort bins
constexpr int   NXCD_ = 8;           // XCDs; blockIdx % 8 -> XCD (round-robin)
constexpr int   EP_   = E_ + 7 * N_ + 64;   // padded edge capacity (lists %8)

// bf16 weight region sizes (elements)
constexpr int   SZ1_ = 128 * 192;    // Wc^T  per block
constexpr int   SZ2_ = 128 * 128;    // w1^T  per block
constexpr int   SZ3_ = 64 * 128;     // w2^T  per block
constexpr int   SZB_ = SZ1_ + SZ2_ + SZ3_;
constexpr int   WTOT_ = NB_ * SZB_;

// workspace layout (bytes)
constexpr size_t SZH_  = (size_t)N_ * ROW_ * sizeof(float);   // fp32 h
constexpr size_t SZHB_ = (size_t)N_ * ROW_ * 2;               // bf16 row image
constexpr size_t OFF_H    = 0;
constexpr size_t OFF_HB   = SZH_;
constexpr size_t OFF_T1B  = OFF_HB  + SZHB_;
constexpr size_t OFF_SB   = OFF_T1B + SZHB_;
constexpr size_t OFF_DEG  = OFF_SB  + SZHB_;
constexpr size_t OFF_CNT  = OFF_DEG + (size_t)N_ * 4;
constexpr size_t OFF_OFFS = OFF_CNT + (size_t)N_ * 4;
constexpr size_t OFF_CV   = ((OFF_OFFS + (size_t)(N_ + 1) * 4 + 255) / 256) * 256;
// esrc (u16[EP_]) + eww (f32[EP_]) live inside the old 8B-cv footprint
constexpr size_t OFF_ESRC = OFF_CV;
constexpr size_t OFF_EW   = ((OFF_ESRC + (size_t)EP_ * 2 + 255) / 256) * 256;
static_assert(OFF_EW + (size_t)EP_ * 4 <= OFF_CV + (size_t)E_ * 8, "cv region overflow");
constexpr size_t OFF_PERM = OFF_CV   + (size_t)E_ * 8;
constexpr size_t OFF_HIST = OFF_PERM + (size_t)N_ * 4;
constexpr size_t OFF_HOFF = OFF_HIST + (size_t)NBIN_ * 4;
constexpr size_t OFF_HFIL = OFF_HOFF + (size_t)NBIN_ * 4;
constexpr size_t OFF_WTC  = OFF_HFIL + (size_t)NBIN_ * 4;
constexpr size_t OFF_WT1  = OFF_WTC + (size_t)NB_ * SZ1_ * 2;
constexpr size_t OFF_WT2  = OFF_WT1 + (size_t)NB_ * SZ2_ * 2;
// total ~210 MB
} // namespace

typedef short s16x8 __attribute__((ext_vector_type(8)));
typedef float f32x4 __attribute__((ext_vector_type(4)));
typedef float f32x2 __attribute__((ext_vector_type(2)));
typedef unsigned int u32;
typedef u32   u32x4 __attribute__((ext_vector_type(4)));
typedef u32   u32x2 __attribute__((ext_vector_type(2)));
typedef unsigned short u16;
typedef u16   u16x8 __attribute__((ext_vector_type(8)));

__device__ __forceinline__ u32 bfr(float x) {
    u32 u = __float_as_uint(x);
    return (u + 0x7FFFu + ((u >> 16) & 1u)) >> 16;
}
__device__ __forceinline__ u32 pack_bf2(float x, float y) {
    return bfr(x) | (bfr(y) << 16);
}
// {lo,hi} bf16 pair -> f32x2 (feeds v_pk_fma_f32)
__device__ __forceinline__ f32x2 bfpair(u32 u) {
    u32x2 r;
    r.x = u << 16;
    r.y = u & 0xFFFF0000u;
    return __builtin_bit_cast(f32x2, r);
}
// swish(o)/1.1 with hardware rcp: o * rcp(1.1 + 1.1*exp(-o*sp))
// (r12: the IEEE 1/x divide sequence was ~10 VALU inst x 64/thread; rcpf is 1.
//  ~1 ulp f32 error, invisible after bf16 rounding.)
__device__ __forceinline__ float swish11(float o, float sp) {
    float e = __expf(-o * sp);
    return o * __builtin_amdgcn_rcpf(__builtin_fmaf(1.1f, e, 1.1f));
}

// ---------------------------------------------------------------- graph prep
__global__ void deg_cnt_k(const int* __restrict__ src, const int* __restrict__ dst,
                          const float* __restrict__ ew,
                          float* __restrict__ deg, int* __restrict__ cnt) {
    int e = blockIdx.x * 256 + threadIdx.x;
    if (e < E_) {
        atomicAdd(deg + src[e], ew[e]);
        atomicAdd(cnt + dst[e], 1);
    }
}

__global__ void dinv_k(float* __restrict__ deg) {
    int i = blockIdx.x * 256 + threadIdx.x;
    if (i < N_) {
        float d = deg[i];
        deg[i] = (d > 0.f) ? rsqrtf(fmaxf(d, 1e-12f)) : 0.f;
    }
}

// exclusive scan of per-node counts PADDED to multiples of 8 (branch-free spmm)
__global__ __launch_bounds__(1024) void scan_k(const int* __restrict__ cnt,
                                               int* __restrict__ offs) {
    __shared__ int sums[1024];
    const int tid = threadIdx.x;
    constexpr int CH = (N_ + 1023) / 1024;   // 20
    const int base = tid * CH;
    int local = 0;
    for (int j = 0; j < CH; ++j) {
        int i = base + j;
        if (i < N_) local += (cnt[i] + 7) & ~7;
    }
    sums[tid] = local;
    __syncthreads();
    for (int off = 1; off < 1024; off <<= 1) {
        int v = sums[tid];
        int u = (tid >= off) ? sums[tid - off] : 0;
        __syncthreads();
        sums[tid] = v + u;
        __syncthreads();
    }
    int run = (tid > 0) ? sums[tid - 1] : 0;
    for (int j = 0; j < CH; ++j) {
        int i = base + j;
        if (i < N_) { offs[i] = run; run += (cnt[i] + 7) & ~7; }
    }
    if (tid == 1023) offs[N_] = sums[1023];
}

// degree histogram / scan / perm-scatter (degree-sorted node order)
__global__ void hist_k(const int* __restrict__ cnt, int* __restrict__ hist) {
    int i = blockIdx.x * 256 + threadIdx.x;
    if (i < N_) atomicAdd(hist + min(cnt[i], NBIN_ - 1), 1);
}

__global__ __launch_bounds__(1024) void hscan_k(const int* __restrict__ hist,
                                                int* __restrict__ hoffs) {
    __shared__ int s[NBIN_];
    int t = threadIdx.x;
    s[t] = hist[t];
    __syncthreads();
    for (int off = 1; off < NBIN_; off <<= 1) {
        int v = s[t];
        int u = (t >= off) ? s[t - off] : 0;
        __syncthreads();
        s[t] = v + u;
        __syncthreads();
    }
    hoffs[t] = (t > 0) ? s[t - 1] : 0;
}

__global__ void permscatter_k(const int* __restrict__ cnt, const int* __restrict__ hoffs,
                              int* __restrict__ hfill, int* __restrict__ perm) {
    int i = blockIdx.x * 256 + threadIdx.x;
    if (i < N_) {
        int b = min(cnt[i], NBIN_ - 1);
        int pos = hoffs[b] + atomicAdd(hfill + b, 1);
        perm[pos] = i;
    }
}

// split edge store: u16 src + f32 weight (6B/edge). pads stay 0 (memset).
__global__ void scatter_k(const int* __restrict__ src, const int* __restrict__ dst,
                          const float* __restrict__ ew, const float* __restrict__ dinv,
                          const int* __restrict__ offs, int* __restrict__ fill,
                          ushort* __restrict__ esrc, float* __restrict__ eww) {
    int e = blockIdx.x * 256 + threadIdx.x;
    if (e < E_) {
        int s = src[e], d = dst[e];
        int pos = offs[d] + atomicAdd(fill + d, 1);
        float w = -dinv[s] * ew[e] * dinv[d];
        esrc[pos] = (ushort)s;
        eww[pos]  = w;
    }
}

// ---------------------------------------------------------------- bf16 weight prep
__global__ void wprep_k(const float* __restrict__ cw, const float* __restrict__ w1,
                        const float* __restrict__ w2,
                        short* __restrict__ wtc, short* __restrict__ wt1,
                        short* __restrict__ wt2) {
    int idx = blockIdx.x * 256 + threadIdx.x;
    if (idx >= WTOT_) return;
    int b = idx / SZB_;
    int rem = idx - b * SZB_;
    if (rem < SZ1_) {
        int n = rem / 192, k = rem - n * 192;
        int part = k >> 6, c = k & 63;
        const float* base = cw + (size_t)b * 3 * 64 * 128;
        float v;
        if (part == 0)      v = base[c * 128 + n] - base[16384 + c * 128 + n];
        else if (part == 1) v = base[8192 + c * 128 + n];
        else                v = 2.f * base[16384 + c * 128 + n];
        wtc[(size_t)b * SZ1_ + n * 192 + k] = (short)bfr(v);
    } else if (rem < SZ1_ + SZ2_) {
        int r2 = rem - SZ1_;
        int n = r2 >> 7, k = r2 & 127;
        float v = w1[(size_t)b * 16384 + k * 128 + n];
        wt1[(size_t)b * SZ2_ + n * 128 + k] = (short)bfr(v);
    } else {
        int r3 = rem - SZ1_ - SZ2_;
        int n = r3 >> 7, k = r3 & 127;
        float v = w2[(size_t)b * 8192 + k * 64 + n];
        wt2[(size_t)b * SZ3_ + n * 128 + k] = (short)bfr(v);
    }
}

// ---------------------------------------------------------------- transposes
__global__ void transpose_in_k(const float* __restrict__ x, float* __restrict__ h,
                               ushort* __restrict__ hb) {
    int idx = blockIdx.x * 256 + threadIdx.x;
    int c4 = idx & 15;
    int nb = idx >> 4;        // n*B + b
    int b  = nb & (B_ - 1);
    int n  = nb >> 4;
    const float4 v = *(const float4*)(x + ((size_t)b * N_ + n) * C_ + (c4 << 2));
    *(float4*)(h + (size_t)nb * C_ + (c4 << 2)) = v;
    uint2 p;
    p.x = pack_bf2(v.x, v.y);
    p.y = pack_bf2(v.z, v.w);
    *(uint2*)(hb + (size_t)nb * C_ + (c4 << 2)) = p;
}

// ---------------------------------------------------------------- SpMM
// r11 = r7 L2 geometry + r10 issue width. 16 phases x 64 cols: gather slice
// N*128B = 2.56MB fits one XCD L2. XCD-pinned: XCD x runs phases {2x,2x+1}
// slot-ordered. 8 lanes/node x uint4 = the node's full 128B phase slice.
// 8 edges/iter, depth-2 metadata pipeline. Edge lists padded %8 (pads w=0).
__global__ __launch_bounds__(256) void spmm_ph_k(const ushort* __restrict__ in,
                                                 ushort* __restrict__ out,
                                                 const int* __restrict__ offs,
                                                 const ushort* __restrict__ esrc,
                                                 const float* __restrict__ eww,
                                                 const int* __restrict__ perm) {
    const int b     = blockIdx.x;
    const int xcd   = b & (NXCD_ - 1);
    const int slot  = b >> 3;                   // 0..1249
    const int half  = (slot >= NCHK_) ? 1 : 0;
    const int ph    = (xcd << 1) | half;
    const int chunk = slot - (half ? NCHK_ : 0);
    const int g     = threadIdx.x >> 3;         // 0..31 node group
    const int lane8 = threadIdx.x & 7;
    const int n = perm[chunk * NPB_ + g];
    const int s0 = offs[n], s1 = offs[n + 1];
    const ushort* inp = in + (size_t)ph * PCOL_ + (lane8 << 3);

    f32x2 a0 = {0.f, 0.f}, a1 = {0.f, 0.f}, a2 = {0.f, 0.f}, a3 = {0.f, 0.f};
    if (s0 < s1) {
        // depth-2 metadata pipeline (reads past s1 stay inside EP_ pad)
        u16x8 sCur = *(const u16x8*)(esrc + s0);
        f32x4 wCurA = *(const f32x4*)(eww + s0);
        f32x4 wCurB = *(const f32x4*)(eww + s0 + 4);
        u16x8 sMid = *(const u16x8*)(esrc + s0 + 8);
        f32x4 wMidA = *(const f32x4*)(eww + s0 + 8);
        f32x4 wMidB = *(const f32x4*)(eww + s0 + 12);
        for (int i = s0; i < s1; i += 8) {
            u32x4 v0 = *(const u32x4*)(inp + ((u32)sCur[0] << 10));
            u32x4 v1 = *(const u32x4*)(inp + ((u32)sCur[1] << 10));
            u32x4 v2 = *(const u32x4*)(inp + ((u32)sCur[2] << 10));
            u32x4 v3 = *(const u32x4*)(inp + ((u32)sCur[3] << 10));
            u32x4 v4 = *(const u32x4*)(inp + ((u32)sCur[4] << 10));
            u32x4 v5 = *(const u32x4*)(inp + ((u32)sCur[5] << 10));
            u32x4 v6 = *(const u32x4*)(inp + ((u32)sCur[6] << 10));
            u32x4 v7 = *(const u32x4*)(inp + ((u32)sCur[7] << 10));
            u16x8 sFar = *(const u16x8*)(esrc + i + 16);
            f32x4 wFarA = *(const f32x4*)(eww + i + 16);
            f32x4 wFarB = *(const f32x4*)(eww + i + 20);
            a0 += (f32x2){wCurA.x, wCurA.x} * bfpair(v0.x);
            a1 += (f32x2){wCurA.x, wCurA.x} * bfpair(v0.y);
            a2 += (f32x2){wCurA.x, wCurA.x} * bfpair(v0.z);
            a3 += (f32x2){wCurA.x, wCurA.x} * bfpair(v0.w);
            a0 += (f32x2){wCurA.y, wCurA.y} * bfpair(v1.x);
            a1 += (f32x2){wCurA.y, wCurA.y} * bfpair(v1.y);
            a2 += (f32x2){wCurA.y, wCurA.y} * bfpair(v1.z);
            a3 += (f32x2){wCurA.y, wCurA.y} * bfpair(v1.w);
            a0 += (f32x2){wCurA.z, wCurA.z} * bfpair(v2.x);
            a1 += (f32x2){wCurA.z, wCurA.z} * bfpair(v2.y);
            a2 += (f32x2){wCurA.z, wCurA.z} * bfpair(v2.z);
            a3 += (f32x2){wCurA.z, wCurA.z} * bfpair(v2.w);
            a0 += (f32x2){wCurA.w, wCurA.w} * bfpair(v3.x);
            a1 += (f32x2){wCurA.w, wCurA.w} * bfpair(v3.y);
            a2 += (f32x2){wCurA.w, wCurA.w} * bfpair(v3.z);
            a3 += (f32x2){wCurA.w, wCurA.w} * bfpair(v3.w);
            a0 += (f32x2){wCurB.x, wCurB.x} * bfpair(v4.x);
            a1 += (f32x2){wCurB.x, wCurB.x} * bfpair(v4.y);
            a2 += (f32x2){wCurB.x, wCurB.x} * bfpair(v4.z);
            a3 += (f32x2){wCurB.x, wCurB.x} * bfpair(v4.w);
            a0 += (f32x2){wCurB.y, wCurB.y} * bfpair(v5.x);
            a1 += (f32x2){wCurB.y, wCurB.y} * bfpair(v5.y);
            a2 += (f32x2){wCurB.y, wCurB.y} * bfpair(v5.z);
            a3 += (f32x2){wCurB.y, wCurB.y} * bfpair(v5.w);
            a0 += (f32x2){wCurB.z, wCurB.z} * bfpair(v6.x);
            a1 += (f32x2){wCurB.z, wCurB.z} * bfpair(v6.y);
            a2 += (f32x2){wCurB.z, wCurB.z} * bfpair(v6.z);
            a3 += (f32x2){wCurB.z, wCurB.z} * bfpair(v6.w);
            a0 += (f32x2){wCurB.w, wCurB.w} * bfpair(v7.x);
            a1 += (f32x2){wCurB.w, wCurB.w} * bfpair(v7.y);
            a2 += (f32x2){wCurB.w, wCurB.w} * bfpair(v7.z);
            a3 += (f32x2){wCurB.w, wCurB.w} * bfpair(v7.w);
            sCur = sMid; wCurA = wMidA; wCurB = wMidB;
            sMid = sFar; wMidA = wFarA; wMidB = wFarB;
        }
    }
    u32x4 p;
    p.x = pack_bf2(a0.x, a0.y);
    p.y = pack_bf2(a1.x, a1.y);
    p.z = pack_bf2(a2.x, a2.y);
    p.w = pack_bf2(a3.x, a3.y);
    *(u32x4*)(out + (size_t)n * ROW_ + (size_t)ph * PCOL_ + (lane8 << 3)) = p;
}

// ---------------------------------------------------------------- MFMA MLP block
// Column-sliced wave partition (r6). r12: swish via v_rcp_f32 (kills the IEEE
// divide sequence, ~600 VALU inst/thread); final block (fin=1) writes directly
// to out[B,N,C] and skips the dead h/hb writes -- transpose_out eliminated.
__global__ __launch_bounds__(256, 4) void mlp_mfma_k(
        float* __restrict__ h, ushort* __restrict__ hb,
        const ushort* __restrict__ t1b, const ushort* __restrict__ sb,
        const short* __restrict__ wtc, const short* __restrict__ wt1,
        const short* __restrict__ wt2,
        const float* __restrict__ cbias, const float* __restrict__ b1,
        const float* __restrict__ b2, const float* __restrict__ betap,
        float* __restrict__ outp, const int fin) {
    __shared__ __align__(16) short u[64 * LDP];

    const int tid  = threadIdx.x;
    const int wv   = tid >> 6;
    const int lane = tid & 63;
    const int m    = lane & 15;
    const int q    = lane >> 4;
    const int row0 = blockIdx.x * 64;
    const float sp = __logf(1.f + __expf(betap[0]));

    // ---- stage-1 weight fragments (12): cols n = wv*32 + t*16 + m, k = kb*32+q*8
    s16x8 wA[6][2];
#pragma unroll
    for (int kb = 0; kb < 6; ++kb)
#pragma unroll
        for (int t = 0; t < 2; ++t)
            wA[kb][t] = *(const s16x8*)(wtc + ((wv << 5) + (t << 4) + m) * 192
                                            + (kb << 5) + (q << 3));

    // ---- cooperative A-tile fill: [64 rows][192 cols] = [hb|t1b|sb], batched
    {
        const ushort* srcs[3] = { hb, t1b, sb };
        s16x8 tv[3][2];
#pragma unroll
        for (int s = 0; s < 3; ++s)
#pragma unroll
            for (int i = 0; i < 2; ++i) {
                int ck = tid + (i << 8);            // 0..511
                int r = ck >> 3, c8 = ck & 7;
                tv[s][i] = *(const s16x8*)(srcs[s] + (size_t)(row0 + r) * C_ + (c8 << 3));
            }
#pragma unroll
        for (int s = 0; s < 3; ++s)
#pragma unroll
            for (int i = 0; i < 2; ++i) {
                int ck = tid + (i << 8);
                int r = ck >> 3, c8 = ck & 7;
                *(s16x8*)(u + r * LDP + (s << 6) + (c8 << 3)) = tv[s][i];
            }
    }
    __syncthreads();

    // ---- stage 1: A(64x192) @ Wc^T-slice -> acc[rg][t] (64 rows x 32 cols/wave)
    f32x4 acc[4][2];
#pragma unroll
    for (int rg = 0; rg < 4; ++rg)
#pragma unroll
        for (int t = 0; t < 2; ++t) acc[rg][t] = (f32x4){0.f, 0.f, 0.f, 0.f};
#pragma unroll
    for (int kb = 0; kb < 6; ++kb)
#pragma unroll
        for (int rg = 0; rg < 4; ++rg) {
            s16x8 af = *(const s16x8*)(u + ((rg << 4) + m) * LDP + (kb << 5) + (q << 3));
            acc[rg][0] = __builtin_amdgcn_mfma_f32_16x16x32_bf16(af, wA[kb][0], acc[rg][0], 0, 0, 0);
            acc[rg][1] = __builtin_amdgcn_mfma_f32_16x16x32_bf16(af, wA[kb][1], acc[rg][1], 0, 0, 0);
        }
    __syncthreads();   // all waves done reading A-tile; u now becomes g1

    // stage-2 weight prefetch (overlaps epilogue-1 VALU; wA is dead now)
    s16x8 wB[4][2];
#pragma unroll
    for (int k4 = 0; k4 < 4; ++k4)
#pragma unroll
        for (int t = 0; t < 2; ++t)
            wB[k4][t] = *(const s16x8*)(wt1 + (((wv << 5) + (t << 4) + m) << 7)
                                            + (k4 << 5) + (q << 3));

    // ---- epilogue 1: bias + swish -> g1 (cols wv*32..wv*32+31, all 64 rows)
    {
        float cb0 = cbias[(wv << 5) + m];
        float cb1 = cbias[(wv << 5) + 16 + m];
#pragma unroll
        for (int rg = 0; rg < 4; ++rg)
#pragma unroll
            for (int t = 0; t < 2; ++t) {
                float bv = t ? cb1 : cb0;
#pragma unroll
                for (int r = 0; r < 4; ++r) {
                    float g = swish11(acc[rg][t][r] + bv, sp);
                    u[((rg << 4) + (q << 2) + r) * LDP + (wv << 5) + (t << 4) + m] =
                        (short)bfr(g);
                }
            }
    }
    __syncthreads();

    // ---- stage 2: g1(64x128) @ w1^T-slice
    f32x4 acc2[4][2];
#pragma unroll
    for (int rg = 0; rg < 4; ++rg)
#pragma unroll
        for (int t = 0; t < 2; ++t) acc2[rg][t] = (f32x4){0.f, 0.f, 0.f, 0.f};
#pragma unroll
    for (int k4 = 0; k4 < 4; ++k4)
#pragma unroll
        for (int rg = 0; rg < 4; ++rg) {
            s16x8 af = *(const s16x8*)(u + ((rg << 4) + m) * LDP + (k4 << 5) + (q << 3));
            acc2[rg][0] = __builtin_amdgcn_mfma_f32_16x16x32_bf16(af, wB[k4][0], acc2[rg][0], 0, 0, 0);
            acc2[rg][1] = __builtin_amdgcn_mfma_f32_16x16x32_bf16(af, wB[k4][1], acc2[rg][1], 0, 0, 0);
        }
    __syncthreads();   // all waves done reading g1; u now becomes g2

    // stage-3 weight prefetch (overlaps epilogue-2 VALU)
    s16x8 wC[4];
#pragma unroll
    for (int k4 = 0; k4 < 4; ++k4)
        wC[k4] = *(const s16x8*)(wt2 + (((wv << 4) + m) << 7) + (k4 << 5) + (q << 3));

    // ---- epilogue 2: bias + swish -> g2
    {
        float b10 = b1[(wv << 5) + m];
        float b11 = b1[(wv << 5) + 16 + m];
#pragma unroll
        for (int rg = 0; rg < 4; ++rg)
#pragma unroll
            for (int t = 0; t < 2; ++t) {
                float bv = t ? b11 : b10;
#pragma unroll
                for (int r = 0; r < 4; ++r) {
                    float g = swish11(acc2[rg][t][r] + bv, sp);
                    u[((rg << 4) + (q << 2) + r) * LDP + (wv << 5) + (t << 4) + m] =
                        (short)bfr(g);
                }
            }
    }
    __syncthreads();

    // ---- stage 3: g2(64x128) @ w2^T-slice -> 16 cols/wave
    f32x4 acc3[4];
#pragma unroll
    for (int rg = 0; rg < 4; ++rg) acc3[rg] = (f32x4){0.f, 0.f, 0.f, 0.f};
#pragma unroll
    for (int k4 = 0; k4 < 4; ++k4)
#pragma unroll
        for (int rg = 0; rg < 4; ++rg) {
            s16x8 af = *(const s16x8*)(u + ((rg << 4) + m) * LDP + (k4 << 5) + (q << 3));
            acc3[rg] = __builtin_amdgcn_mfma_f32_16x16x32_bf16(af, wC[k4], acc3[rg], 0, 0, 0);
        }

    // ---- epilogue 3: residual h += f; non-final refreshes h/hb, final writes
    // straight to out[B,N,C] (transpose fused; dead h/hb writes skipped)
    {
        float b2v = b2[(wv << 4) + m];
        float hv[4][4];
#pragma unroll
        for (int rg = 0; rg < 4; ++rg)
#pragma unroll
            for (int r = 0; r < 4; ++r)
                hv[rg][r] = h[(size_t)(row0 + (rg << 4) + (q << 2) + r) * C_
                              + (wv << 4) + m];
        if (fin) {
#pragma unroll
            for (int rg = 0; rg < 4; ++rg)
#pragma unroll
                for (int r = 0; r < 4; ++r) {
                    int row = row0 + (rg << 4) + (q << 2) + r;
                    int nn = row >> 4, bb = row & 15;
                    outp[((size_t)bb * N_ + nn) * C_ + (wv << 4) + m] =
                        hv[rg][r] + acc3[rg][r] + b2v;
                }
        } else {
#pragma unroll
            for (int rg = 0; rg < 4; ++rg)
#pragma unroll
                for (int r = 0; r < 4; ++r) {
                    size_t eidx = (size_t)(row0 + (rg << 4) + (q << 2) + r) * C_
                                  + (wv << 4) + m;
                    float nv = hv[rg][r] + acc3[rg][r] + b2v;
                    h[eidx]  = nv;
                    hb[eidx] = (ushort)bfr(nv);
                }
        }
    }
}

// ---------------------------------------------------------------- launch
extern "C" void kernel_launch(void* const* d_in, const int* in_sizes, int n_in,
                              void* d_out, int out_size, void* d_ws, size_t ws_size,
                              hipStream_t stream) {
    const float* x    = (const float*)d_in[0];
    const int*   ei   = (const int*)d_in[1];
    const float* ew   = (const float*)d_in[2];
    const float* cw   = (const float*)d_in[3];
    const float* cb   = (const float*)d_in[4];
    const float* beta = (const float*)d_in[5];
    const float* w1   = (const float*)d_in[6];
    const float* b1   = (const float*)d_in[7];
    const float* w2   = (const float*)d_in[8];
    const float* b2   = (const float*)d_in[9];
    float* out = (float*)d_out;

    char* ws = (char*)d_ws;
    float*  h_t  = (float*) (ws + OFF_H);
    ushort* hb   = (ushort*)(ws + OFF_HB);
    ushort* t1b  = (ushort*)(ws + OFF_T1B);
    ushort* sb   = (ushort*)(ws + OFF_SB);
    float*  deg  = (float*) (ws + OFF_DEG);
    int*    cnt  = (int*)   (ws + OFF_CNT);
    int*    offs = (int*)   (ws + OFF_OFFS);
    ushort* esrc = (ushort*)(ws + OFF_ESRC);
    float*  eww  = (float*) (ws + OFF_EW);
    int*    perm = (int*)   (ws + OFF_PERM);
    int*    hist = (int*)   (ws + OFF_HIST);
    int*    hoff = (int*)   (ws + OFF_HOFF);
    int*    hfil = (int*)   (ws + OFF_HFIL);
    short*  wtc  = (short*) (ws + OFF_WTC);
    short*  wt1  = (short*) (ws + OFF_WT1);
    short*  wt2  = (short*) (ws + OFF_WT2);

    const int* srcI = ei;
    const int* dstI = ei + E_;

    // graph prep
    hipMemsetAsync(deg, 0, (size_t)N_ * 4, stream);
    hipMemsetAsync(cnt, 0, (size_t)N_ * 4, stream);
    hipMemsetAsync(hist, 0, (size_t)NBIN_ * 4, stream);
    hipMemsetAsync(hfil, 0, (size_t)NBIN_ * 4, stream);
    hipMemsetAsync(esrc, 0, (size_t)EP_ * 2, stream);   // pad entries: src=0
    hipMemsetAsync(eww,  0, (size_t)EP_ * 4, stream);   // pad entries: w=0
    deg_cnt_k<<<(E_ + 255) / 256, 256, 0, stream>>>(srcI, dstI, ew, deg, cnt);
    dinv_k<<<(N_ + 255) / 256, 256, 0, stream>>>(deg);
    scan_k<<<1, 1024, 0, stream>>>(cnt, offs);
    hist_k<<<(N_ + 255) / 256, 256, 0, stream>>>(cnt, hist);
    hscan_k<<<1, NBIN_, 0, stream>>>(hist, hoff);
    permscatter_k<<<(N_ + 255) / 256, 256, 0, stream>>>(cnt, hoff, hfil, perm);
    hipMemsetAsync(cnt, 0, (size_t)N_ * 4, stream);
    scatter_k<<<(E_ + 255) / 256, 256, 0, stream>>>(srcI, dstI, ew, deg, offs, cnt,
                                                    esrc, eww);

    // bf16 weights
    wprep_k<<<(WTOT_ + 255) / 256, 256, 0, stream>>>(cw, w1, w2, wtc, wt1, wt2);

    // x -> [N,B,C] (fp32 + bf16 image)
    transpose_in_k<<<(N_ * B_ * 16) / 256, 256, 0, stream>>>(x, h_t, hb);

    for (int b = 0; b < NB_; ++b) {
        spmm_ph_k<<<PH_ * NCHK_, 256, 0, stream>>>(hb, t1b, offs, esrc, eww, perm);
        spmm_ph_k<<<PH_ * NCHK_, 256, 0, stream>>>(t1b, sb, offs, esrc, eww, perm);
        mlp_mfma_k<<<NR_ / 64, 256, 0, stream>>>(h_t, hb, t1b, sb,
                                                 wtc + (size_t)b * SZ1_,
                                                 wt1 + (size_t)b * SZ2_,
                                                 wt2 + (size_t)b * SZ3_,
                                                 cb + (size_t)b * DIM_,
                                                 b1 + (size_t)b * DIM_,
                                                 b2 + (size_t)b * C_,
                                                 beta + b,
                                                 out, (b == NB_ - 1) ? 1 : 0);
    }
}